// Round 1
// baseline (655.256 us; speedup 1.0000x reference)
//
#include <hip/hip_runtime.h>

#define NN 50000
#define NE 800000

typedef __attribute__((ext_vector_type(8))) short short8;
typedef __attribute__((ext_vector_type(4))) float f32x4;

__device__ __forceinline__ float bf2f(short u) {
    union { unsigned int i; float f; } c;
    c.i = ((unsigned int)(unsigned short)u) << 16;
    return c.f;
}
__device__ __forceinline__ short f2bf(float f) {
    union { float f; unsigned int i; } c; c.f = f;
    unsigned int u = c.i;
    unsigned int r = (u + 0x7FFFu + ((u >> 16) & 1u)) >> 16;
    return (short)r;
}

// ---------- small utility kernels ----------

__global__ void cvt_f32_bf16_kernel(const float* __restrict__ in, short* __restrict__ out, int n) {
    int gid = blockIdx.x * 256 + threadIdx.x;
    if (gid < n) out[gid] = f2bf(in[gid]);
}

// W [K][Dout] f32  ->  Wt [Dout][K] bf16
__global__ void wcvt_kernel(const float* __restrict__ W, short* __restrict__ Wt, int K, int Dout) {
    int gid = blockIdx.x * 256 + threadIdx.x;
    if (gid >= K * Dout) return;
    int d = gid / K;
    int k = gid - d * K;
    Wt[gid] = f2bf(W[(long)k * Dout + d]);
}

__global__ void hist_kernel(const int* __restrict__ dst, int* __restrict__ cnt, int E) {
    int gid = blockIdx.x * 256 + threadIdx.x;
    if (gid < E) atomicAdd(&cnt[dst[gid]], 1);
}

// single block, 256 threads: exclusive scan of cnt[0..n) -> row_start, cursor
__global__ void scan_kernel(const int* __restrict__ cnt, int* __restrict__ row_start,
                            int* __restrict__ cursor, int n) {
    __shared__ int partial[256];
    int t = threadIdx.x;
    int chunk = (n + 255) / 256;
    int lo = t * chunk;
    int hi = lo + chunk; if (hi > n) hi = n; if (lo > n) lo = n;
    int s = 0;
    for (int i = lo; i < hi; ++i) s += cnt[i];
    partial[t] = s;
    __syncthreads();
    for (int off = 1; off < 256; off <<= 1) {
        int v = partial[t];
        int add = (t >= off) ? partial[t - off] : 0;
        __syncthreads();
        partial[t] = v + add;
        __syncthreads();
    }
    int base = (t == 0) ? 0 : partial[t - 1];
    for (int i = lo; i < hi; ++i) {
        row_start[i] = base;
        cursor[i] = base;
        base += cnt[i];
    }
}

__global__ void build_kernel(const int* __restrict__ src, const int* __restrict__ dst,
                             int* __restrict__ cursor, int* __restrict__ srcs, int E) {
    int gid = blockIdx.x * 256 + threadIdx.x;
    if (gid >= E) return;
    int slot = atomicAdd(&cursor[dst[gid]], 1);
    srcs[slot] = src[gid];
}

// one block per node; thread t owns feature column t
__global__ __launch_bounds__(256) void gather_mean_kernel(
    const short* __restrict__ h, const int* __restrict__ srcs,
    const int* __restrict__ row_start, const int* __restrict__ cnt,
    short* __restrict__ nb, int D)
{
    int v = blockIdx.x;
    int t = threadIdx.x;
    if (t >= D) return;
    int c = cnt[v];
    int rs = row_start[v];
    float acc = 0.f;
    int i = 0;
    for (; i + 4 <= c; i += 4) {
        int s0 = srcs[rs + i + 0];
        int s1 = srcs[rs + i + 1];
        int s2 = srcs[rs + i + 2];
        int s3 = srcs[rs + i + 3];
        float f0 = bf2f(h[(long)s0 * D + t]);
        float f1 = bf2f(h[(long)s1 * D + t]);
        float f2 = bf2f(h[(long)s2 * D + t]);
        float f3 = bf2f(h[(long)s3 * D + t]);
        acc += (f0 + f1) + (f2 + f3);
    }
    for (; i < c; ++i) acc += bf2f(h[(long)srcs[rs + i] * D + t]);
    float inv = (c > 0) ? (1.0f / (float)c) : 0.0f;
    nb[(long)v * D + t] = f2bf(acc * inv);
}

// fused SAGE layer GEMM: out = act(Aself@Bself^T + Aneigh@Bneigh^T + bias)
// A* : [M][K] bf16 row-major; B* : [Nout][K] bf16 (pre-transposed weights)
// 4 waves, 2x2 wave grid, 32x32 per wave via 2x2 frags of 16x16x32.
template<bool RELU, bool OUT_F32>
__global__ __launch_bounds__(256) void gemm_sage_kernel(
    const short* __restrict__ Aself, const short* __restrict__ Aneigh,
    const short* __restrict__ Bself, const short* __restrict__ Bneigh,
    const float* __restrict__ bias, void* __restrict__ outp,
    int M, int K, int Nout)
{
    const int tid = threadIdx.x;
    const int wave = tid >> 6;
    const int lane = tid & 63;
    const int wm = wave & 1, wn = wave >> 1;
    const int l15 = lane & 15;
    const int kg = lane >> 4;            // 0..3
    const int bm = blockIdx.x * 64 + wm * 32;
    const int bn = blockIdx.y * 64 + wn * 32;

    f32x4 acc[2][2];
    #pragma unroll
    for (int a = 0; a < 2; ++a)
        #pragma unroll
        for (int b = 0; b < 2; ++b)
            acc[a][b] = (f32x4){0.f, 0.f, 0.f, 0.f};

    const int arow0 = bm + l15, arow1 = bm + 16 + l15;
    const int bcol0 = bn + l15, bcol1 = bn + 16 + l15;
    const bool a0ok = arow0 < M, a1ok = arow1 < M;
    const short8 zero8 = {0, 0, 0, 0, 0, 0, 0, 0};

    #pragma unroll
    for (int ph = 0; ph < 2; ++ph) {
        const short* __restrict__ A = ph ? Aneigh : Aself;
        const short* __restrict__ B = ph ? Bneigh : Bself;
        const short* a0p = A + (long)arow0 * K + kg * 8;
        const short* a1p = A + (long)arow1 * K + kg * 8;
        const short* b0p = B + (long)bcol0 * K + kg * 8;
        const short* b1p = B + (long)bcol1 * K + kg * 8;
        for (int k0 = 0; k0 < K; k0 += 32) {
            short8 a0 = a0ok ? *(const short8*)(a0p + k0) : zero8;
            short8 a1 = a1ok ? *(const short8*)(a1p + k0) : zero8;
            short8 b0 = *(const short8*)(b0p + k0);
            short8 b1 = *(const short8*)(b1p + k0);
            acc[0][0] = __builtin_amdgcn_mfma_f32_16x16x32_bf16(a0, b0, acc[0][0], 0, 0, 0);
            acc[0][1] = __builtin_amdgcn_mfma_f32_16x16x32_bf16(a0, b1, acc[0][1], 0, 0, 0);
            acc[1][0] = __builtin_amdgcn_mfma_f32_16x16x32_bf16(a1, b0, acc[1][0], 0, 0, 0);
            acc[1][1] = __builtin_amdgcn_mfma_f32_16x16x32_bf16(a1, b1, acc[1][1], 0, 0, 0);
        }
    }

    #pragma unroll
    for (int fm = 0; fm < 2; ++fm) {
        int rowbase = bm + fm * 16 + kg * 4;
        #pragma unroll
        for (int fn = 0; fn < 2; ++fn) {
            int col = bn + fn * 16 + l15;
            float bv = bias[col];
            #pragma unroll
            for (int r = 0; r < 4; ++r) {
                int row = rowbase + r;
                if (row < M) {
                    float vv = acc[fm][fn][r] + bv;
                    if (RELU) vv = fmaxf(vv, 0.f);
                    if (OUT_F32) ((float*)outp)[(long)row * Nout + col] = vv;
                    else         ((short*)outp)[(long)row * Nout + col] = f2bf(vv);
                }
            }
        }
    }
}

// ---------- launch ----------

extern "C" void kernel_launch(void* const* d_in, const int* in_sizes, int n_in,
                              void* d_out, int out_size, void* d_ws, size_t ws_size,
                              hipStream_t stream) {
    const float* x    = (const float*)d_in[0];
    const int*   srcp = (const int*)d_in[1];
    const int*   dstp = (const int*)d_in[2];
    const float* Ws0  = (const float*)d_in[3];
    const float* Wn0  = (const float*)d_in[4];
    const float* b0   = (const float*)d_in[5];
    const float* Ws1  = (const float*)d_in[6];
    const float* Wn1  = (const float*)d_in[7];
    const float* b1   = (const float*)d_in[8];
    const float* Ws2  = (const float*)d_in[9];
    const float* Wn2  = (const float*)d_in[10];
    const float* b2   = (const float*)d_in[11];

    char* base = (char*)d_ws;
    size_t off = 0;
    auto alloc = [&](size_t bytes) -> void* {
        void* p = base + off;
        off += (bytes + 255) & ~(size_t)255;
        return p;
    };

    int*   cnt       = (int*)alloc((size_t)NN * 4);
    int*   row_start = (int*)alloc((size_t)NN * 4);
    int*   cursor    = (int*)alloc((size_t)NN * 4);
    int*   srcs      = (int*)alloc((size_t)NE * 4);
    short* hA        = (short*)alloc((size_t)NN * 256 * 2);
    short* hB        = (short*)alloc((size_t)NN * 256 * 2);
    short* nb        = (short*)alloc((size_t)NN * 256 * 2);
    short* wts       = (short*)alloc((size_t)262144 * 2);
    short* Wt0s = wts;            // [256][128]
    short* Wt0n = Wt0s + 32768;   // [256][128]
    short* Wt1s = Wt0n + 32768;   // [256][256]
    short* Wt1n = Wt1s + 65536;   // [256][256]
    short* Wt2s = Wt1n + 65536;   // [128][256]
    short* Wt2n = Wt2s + 32768;   // [128][256]

    // CSR build (dst-sorted src list)
    hipMemsetAsync(cnt, 0, (size_t)NN * 4, stream);
    hist_kernel<<<(NE + 255) / 256, 256, 0, stream>>>(dstp, cnt, NE);
    scan_kernel<<<1, 256, 0, stream>>>(cnt, row_start, cursor, NN);
    build_kernel<<<(NE + 255) / 256, 256, 0, stream>>>(srcp, dstp, cursor, srcs, NE);

    // weight conversion/transpose to bf16 [Dout][K]
    wcvt_kernel<<<(32768 + 255) / 256, 256, 0, stream>>>(Ws0, Wt0s, 128, 256);
    wcvt_kernel<<<(32768 + 255) / 256, 256, 0, stream>>>(Wn0, Wt0n, 128, 256);
    wcvt_kernel<<<(65536 + 255) / 256, 256, 0, stream>>>(Ws1, Wt1s, 256, 256);
    wcvt_kernel<<<(65536 + 255) / 256, 256, 0, stream>>>(Wn1, Wt1n, 256, 256);
    wcvt_kernel<<<(32768 + 255) / 256, 256, 0, stream>>>(Ws2, Wt2s, 256, 128);
    wcvt_kernel<<<(32768 + 255) / 256, 256, 0, stream>>>(Wn2, Wt2n, 256, 128);

    // x -> bf16
    cvt_f32_bf16_kernel<<<(NN * 128 + 255) / 256, 256, 0, stream>>>(x, hA, NN * 128);

    const int mblocks = (NN + 63) / 64;   // 782

    // layer 0: h0 [N,128] -> h1 [N,256] (relu)
    gather_mean_kernel<<<NN, 256, 0, stream>>>(hA, srcs, row_start, cnt, nb, 128);
    gemm_sage_kernel<true, false><<<dim3(mblocks, 4), 256, 0, stream>>>(
        hA, nb, Wt0s, Wt0n, b0, hB, NN, 128, 256);

    // layer 1: h1 [N,256] -> h2 [N,256] (relu)
    gather_mean_kernel<<<NN, 256, 0, stream>>>(hB, srcs, row_start, cnt, nb, 256);
    gemm_sage_kernel<true, false><<<dim3(mblocks, 4), 256, 0, stream>>>(
        hB, nb, Wt1s, Wt1n, b1, hA, NN, 256, 256);

    // layer 2: h2 [N,256] -> out [N,128] f32 (no relu)
    gather_mean_kernel<<<NN, 256, 0, stream>>>(hA, srcs, row_start, cnt, nb, 256);
    gemm_sage_kernel<false, true><<<dim3(mblocks, 2), 256, 0, stream>>>(
        hA, nb, Wt2s, Wt2n, b2, d_out, NN, 256, 128);
}

// Round 2
// 467.551 us; speedup vs baseline: 1.4015x; 1.4015x over previous
//
#include <hip/hip_runtime.h>

#define NN 50000
#define NE 800000
#define NB1 196   // ceil(NN/256)

typedef __attribute__((ext_vector_type(8))) short short8;
typedef __attribute__((ext_vector_type(4))) float f32x4;

__device__ __forceinline__ float bf2f(short u) {
    union { unsigned int i; float f; } c;
    c.i = ((unsigned int)(unsigned short)u) << 16;
    return c.f;
}
__device__ __forceinline__ short f2bf(float f) {
    union { float f; unsigned int i; } c; c.f = f;
    unsigned int u = c.i;
    unsigned int r = (u + 0x7FFFu + ((u >> 16) & 1u)) >> 16;
    return (short)r;
}

// ---------- small utility kernels ----------

__global__ void cvt_f32_bf16_kernel(const float* __restrict__ in, short* __restrict__ out, int n) {
    int gid = blockIdx.x * 256 + threadIdx.x;
    if (gid < n) out[gid] = f2bf(in[gid]);
}

// all six weight transposes in one launch; wts layout fixed (see kernel_launch)
__global__ void wcvt_all_kernel(const float* __restrict__ Ws0, const float* __restrict__ Wn0,
                                const float* __restrict__ Ws1, const float* __restrict__ Wn1,
                                const float* __restrict__ Ws2, const float* __restrict__ Wn2,
                                short* __restrict__ wts) {
    int gid = blockIdx.x * 256 + threadIdx.x;   // 0..262143
    const float* W; int K, Dout, loc;
    if (gid < 65536)       { K = 128; Dout = 256; W = (gid < 32768)  ? Ws0 : Wn0; loc = gid & 32767; }
    else if (gid < 196608) { K = 256; Dout = 256; W = (gid < 131072) ? Ws1 : Wn1; loc = (gid - 65536) & 65535; }
    else                   { K = 256; Dout = 128; W = (gid < 229376) ? Ws2 : Wn2; loc = (gid - 196608) & 32767; }
    int d = loc / K, k = loc - d * K;
    wts[gid] = f2bf(W[(long)k * Dout + d]);
}

__global__ void hist_kernel(const int* __restrict__ dst, int* __restrict__ cnt, int E) {
    int gid = blockIdx.x * 256 + threadIdx.x;
    if (gid < E) atomicAdd(&cnt[dst[gid]], 1);
}

// ---------- 3-phase parallel exclusive scan over cnt[0..NN) ----------

__global__ __launch_bounds__(256) void blocksum_kernel(const int* __restrict__ cnt,
                                                       int* __restrict__ bsum, int n) {
    __shared__ int sm[256];
    int t = threadIdx.x;
    int idx = blockIdx.x * 256 + t;
    sm[t] = (idx < n) ? cnt[idx] : 0;
    __syncthreads();
    for (int off = 128; off > 0; off >>= 1) {
        if (t < off) sm[t] += sm[t + off];
        __syncthreads();
    }
    if (t == 0) bsum[blockIdx.x] = sm[0];
}

__global__ __launch_bounds__(256) void scanb_kernel(const int* __restrict__ bsum,
                                                    int* __restrict__ bpre, int nb) {
    __shared__ int sm[256];
    int t = threadIdx.x;
    sm[t] = (t < nb) ? bsum[t] : 0;
    __syncthreads();
    for (int off = 1; off < 256; off <<= 1) {
        int v = sm[t];
        int add = (t >= off) ? sm[t - off] : 0;
        __syncthreads();
        sm[t] = v + add;
        __syncthreads();
    }
    if (t < nb) bpre[t] = (t == 0) ? 0 : sm[t - 1];
}

__global__ __launch_bounds__(256) void scatter_scan_kernel(const int* __restrict__ cnt,
                                                           const int* __restrict__ bpre,
                                                           int* __restrict__ row_start,
                                                           int* __restrict__ cursor, int n) {
    __shared__ int sm[256];
    int t = threadIdx.x;
    int idx = blockIdx.x * 256 + t;
    int val = (idx < n) ? cnt[idx] : 0;
    sm[t] = val;
    __syncthreads();
    for (int off = 1; off < 256; off <<= 1) {
        int v = sm[t];
        int add = (t >= off) ? sm[t - off] : 0;
        __syncthreads();
        sm[t] = v + add;
        __syncthreads();
    }
    int base = bpre[blockIdx.x] + sm[t] - val;   // exclusive prefix
    if (idx < n) { row_start[idx] = base; cursor[idx] = base; }
}

__global__ void build_kernel(const int* __restrict__ src, const int* __restrict__ dst,
                             int* __restrict__ cursor, int* __restrict__ srcs, int E) {
    int gid = blockIdx.x * 256 + threadIdx.x;
    if (gid >= E) return;
    int slot = atomicAdd(&cursor[dst[gid]], 1);
    srcs[slot] = src[gid];
}

// ---------- gather-mean: one wave per node, lane owns DV=D/64 columns ----------

template<int DV>
__global__ __launch_bounds__(256) void gather_mean_kernel(
    const short* __restrict__ h, const int* __restrict__ srcs,
    const int* __restrict__ row_start, const int* __restrict__ cnt,
    short* __restrict__ nb)
{
    typedef __attribute__((ext_vector_type(DV))) short svec;
    const int wave = threadIdx.x >> 6;
    const int lane = threadIdx.x & 63;
    const int v = blockIdx.x * 4 + wave;
    if (v >= NN) return;
    const int c  = cnt[v];
    const int rs = row_start[v];
    float acc[DV];
    #pragma unroll
    for (int j = 0; j < DV; ++j) acc[j] = 0.f;
    const svec* hp = (const svec*)h;   // row = 64 svecs
    int i = 0;
    for (; i + 4 <= c; i += 4) {
        int s0 = srcs[rs + i + 0];
        int s1 = srcs[rs + i + 1];
        int s2 = srcs[rs + i + 2];
        int s3 = srcs[rs + i + 3];
        svec v0 = hp[(long)s0 * 64 + lane];
        svec v1 = hp[(long)s1 * 64 + lane];
        svec v2 = hp[(long)s2 * 64 + lane];
        svec v3 = hp[(long)s3 * 64 + lane];
        #pragma unroll
        for (int j = 0; j < DV; ++j)
            acc[j] += (bf2f(v0[j]) + bf2f(v1[j])) + (bf2f(v2[j]) + bf2f(v3[j]));
    }
    for (; i < c; ++i) {
        svec vv = hp[(long)srcs[rs + i] * 64 + lane];
        #pragma unroll
        for (int j = 0; j < DV; ++j) acc[j] += bf2f(vv[j]);
    }
    float inv = (c > 0) ? (1.0f / (float)c) : 0.0f;
    svec outv;
    #pragma unroll
    for (int j = 0; j < DV; ++j) outv[j] = f2bf(acc[j] * inv);
    ((svec*)nb)[(long)v * 64 + lane] = outv;
}

// ---------- fused SAGE layer GEMM ----------
// out = act(Aself@Bself^T + Aneigh@Bneigh^T + bias)
// A* : [M][K] bf16 row-major; B* : [Nout][K] bf16 (pre-transposed weights)
template<bool RELU, bool OUT_F32>
__global__ __launch_bounds__(256) void gemm_sage_kernel(
    const short* __restrict__ Aself, const short* __restrict__ Aneigh,
    const short* __restrict__ Bself, const short* __restrict__ Bneigh,
    const float* __restrict__ bias, void* __restrict__ outp,
    int M, int K, int Nout)
{
    const int tid = threadIdx.x;
    const int wave = tid >> 6;
    const int lane = tid & 63;
    const int wm = wave & 1, wn = wave >> 1;
    const int l15 = lane & 15;
    const int kg = lane >> 4;            // 0..3
    const int bm = blockIdx.x * 64 + wm * 32;
    const int bn = blockIdx.y * 64 + wn * 32;

    f32x4 acc[2][2];
    #pragma unroll
    for (int a = 0; a < 2; ++a)
        #pragma unroll
        for (int b = 0; b < 2; ++b)
            acc[a][b] = (f32x4){0.f, 0.f, 0.f, 0.f};

    const int arow0 = bm + l15, arow1 = bm + 16 + l15;
    const int bcol0 = bn + l15, bcol1 = bn + 16 + l15;
    const bool a0ok = arow0 < M, a1ok = arow1 < M;
    const short8 zero8 = {0, 0, 0, 0, 0, 0, 0, 0};

    #pragma unroll
    for (int ph = 0; ph < 2; ++ph) {
        const short* __restrict__ A = ph ? Aneigh : Aself;
        const short* __restrict__ B = ph ? Bneigh : Bself;
        const short* a0p = A + (long)arow0 * K + kg * 8;
        const short* a1p = A + (long)arow1 * K + kg * 8;
        const short* b0p = B + (long)bcol0 * K + kg * 8;
        const short* b1p = B + (long)bcol1 * K + kg * 8;
        for (int k0 = 0; k0 < K; k0 += 32) {
            short8 a0 = a0ok ? *(const short8*)(a0p + k0) : zero8;
            short8 a1 = a1ok ? *(const short8*)(a1p + k0) : zero8;
            short8 b0 = *(const short8*)(b0p + k0);
            short8 b1 = *(const short8*)(b1p + k0);
            acc[0][0] = __builtin_amdgcn_mfma_f32_16x16x32_bf16(a0, b0, acc[0][0], 0, 0, 0);
            acc[0][1] = __builtin_amdgcn_mfma_f32_16x16x32_bf16(a0, b1, acc[0][1], 0, 0, 0);
            acc[1][0] = __builtin_amdgcn_mfma_f32_16x16x32_bf16(a1, b0, acc[1][0], 0, 0, 0);
            acc[1][1] = __builtin_amdgcn_mfma_f32_16x16x32_bf16(a1, b1, acc[1][1], 0, 0, 0);
        }
    }

    #pragma unroll
    for (int fm = 0; fm < 2; ++fm) {
        int rowbase = bm + fm * 16 + kg * 4;
        #pragma unroll
        for (int fn = 0; fn < 2; ++fn) {
            int col = bn + fn * 16 + l15;
            float bv = bias[col];
            #pragma unroll
            for (int r = 0; r < 4; ++r) {
                int row = rowbase + r;
                if (row < M) {
                    float vv = acc[fm][fn][r] + bv;
                    if (RELU) vv = fmaxf(vv, 0.f);
                    if (OUT_F32) ((float*)outp)[(long)row * Nout + col] = vv;
                    else         ((short*)outp)[(long)row * Nout + col] = f2bf(vv);
                }
            }
        }
    }
}

// ---------- launch ----------

extern "C" void kernel_launch(void* const* d_in, const int* in_sizes, int n_in,
                              void* d_out, int out_size, void* d_ws, size_t ws_size,
                              hipStream_t stream) {
    const float* x    = (const float*)d_in[0];
    const int*   srcp = (const int*)d_in[1];
    const int*   dstp = (const int*)d_in[2];
    const float* Ws0  = (const float*)d_in[3];
    const float* Wn0  = (const float*)d_in[4];
    const float* b0   = (const float*)d_in[5];
    const float* Ws1  = (const float*)d_in[6];
    const float* Wn1  = (const float*)d_in[7];
    const float* b1   = (const float*)d_in[8];
    const float* Ws2  = (const float*)d_in[9];
    const float* Wn2  = (const float*)d_in[10];
    const float* b2   = (const float*)d_in[11];

    char* base = (char*)d_ws;
    size_t off = 0;
    auto alloc = [&](size_t bytes) -> void* {
        void* p = base + off;
        off += (bytes + 255) & ~(size_t)255;
        return p;
    };

    int*   cnt       = (int*)alloc((size_t)NN * 4);
    int*   row_start = (int*)alloc((size_t)NN * 4);
    int*   cursor    = (int*)alloc((size_t)NN * 4);
    int*   bsum      = (int*)alloc((size_t)NB1 * 4);
    int*   bpre      = (int*)alloc((size_t)NB1 * 4);
    int*   srcs      = (int*)alloc((size_t)NE * 4);
    short* hA        = (short*)alloc((size_t)NN * 256 * 2);
    short* hB        = (short*)alloc((size_t)NN * 256 * 2);
    short* nb        = (short*)alloc((size_t)NN * 256 * 2);
    short* wts       = (short*)alloc((size_t)262144 * 2);
    short* Wt0s = wts;            // [256][128]
    short* Wt0n = Wt0s + 32768;   // [256][128]
    short* Wt1s = Wt0n + 32768;   // [256][256]
    short* Wt1n = Wt1s + 65536;   // [256][256]
    short* Wt2s = Wt1n + 65536;   // [128][256]
    short* Wt2n = Wt2s + 32768;   // [128][256]

    // CSR build (dst-sorted src list)
    hipMemsetAsync(cnt, 0, (size_t)NN * 4, stream);
    hist_kernel<<<(NE + 255) / 256, 256, 0, stream>>>(dstp, cnt, NE);
    blocksum_kernel<<<NB1, 256, 0, stream>>>(cnt, bsum, NN);
    scanb_kernel<<<1, 256, 0, stream>>>(bsum, bpre, NB1);
    scatter_scan_kernel<<<NB1, 256, 0, stream>>>(cnt, bpre, row_start, cursor, NN);
    build_kernel<<<(NE + 255) / 256, 256, 0, stream>>>(srcp, dstp, cursor, srcs, NE);

    // weight conversion/transpose to bf16 [Dout][K], single launch
    wcvt_all_kernel<<<1024, 256, 0, stream>>>(Ws0, Wn0, Ws1, Wn1, Ws2, Wn2, wts);

    // x -> bf16
    cvt_f32_bf16_kernel<<<(NN * 128 + 255) / 256, 256, 0, stream>>>(x, hA, NN * 128);

    const int mblocks = (NN + 63) / 64;   // 782
    const int gblocks = (NN + 3) / 4;     // 12500

    // layer 0: h0 [N,128] -> h1 [N,256] (relu)
    gather_mean_kernel<2><<<gblocks, 256, 0, stream>>>(hA, srcs, row_start, cnt, nb);
    gemm_sage_kernel<true, false><<<dim3(mblocks, 4), 256, 0, stream>>>(
        hA, nb, Wt0s, Wt0n, b0, hB, NN, 128, 256);

    // layer 1: h1 [N,256] -> h2 [N,256] (relu)
    gather_mean_kernel<4><<<gblocks, 256, 0, stream>>>(hB, srcs, row_start, cnt, nb);
    gemm_sage_kernel<true, false><<<dim3(mblocks, 4), 256, 0, stream>>>(
        hB, nb, Wt1s, Wt1n, b1, hA, NN, 256, 256);

    // layer 2: h2 [N,256] -> out [N,128] f32 (no relu)
    gather_mean_kernel<4><<<gblocks, 256, 0, stream>>>(hA, srcs, row_start, cnt, nb);
    gemm_sage_kernel<false, true><<<dim3(mblocks, 2), 256, 0, stream>>>(
        hA, nb, Wt2s, Wt2n, b2, d_out, NN, 256, 128);
}

// Round 3
// 437.127 us; speedup vs baseline: 1.4990x; 1.0696x over previous
//
#include <hip/hip_runtime.h>

#define NN 50000
#define NE 800000
#define NB1 196   // ceil(NN/256)

typedef __attribute__((ext_vector_type(8))) short short8;
typedef __attribute__((ext_vector_type(4))) float f32x4;
typedef unsigned int u32;

__device__ __forceinline__ float bf2f(short u) {
    union { unsigned int i; float f; } c;
    c.i = ((unsigned int)(unsigned short)u) << 16;
    return c.f;
}
__device__ __forceinline__ short f2bf(float f) {
    union { float f; unsigned int i; } c; c.f = f;
    unsigned int u = c.i;
    unsigned int r = (u + 0x7FFFu + ((u >> 16) & 1u)) >> 16;
    return (short)r;
}

// ---------- small utility kernels ----------

__global__ void cvt_f32_bf16_kernel(const float* __restrict__ in, short* __restrict__ out, int n) {
    int gid = blockIdx.x * 256 + threadIdx.x;
    if (gid < n) out[gid] = f2bf(in[gid]);
}

__global__ void wcvt_all_kernel(const float* __restrict__ Ws0, const float* __restrict__ Wn0,
                                const float* __restrict__ Ws1, const float* __restrict__ Wn1,
                                const float* __restrict__ Ws2, const float* __restrict__ Wn2,
                                short* __restrict__ wts) {
    int gid = blockIdx.x * 256 + threadIdx.x;   // 0..262143
    const float* W; int K, Dout, loc;
    if (gid < 65536)       { K = 128; Dout = 256; W = (gid < 32768)  ? Ws0 : Wn0; loc = gid & 32767; }
    else if (gid < 196608) { K = 256; Dout = 256; W = (gid < 131072) ? Ws1 : Wn1; loc = (gid - 65536) & 65535; }
    else                   { K = 256; Dout = 128; W = (gid < 229376) ? Ws2 : Wn2; loc = (gid - 196608) & 32767; }
    int d = loc / K, k = loc - d * K;
    wts[gid] = f2bf(W[(long)k * Dout + d]);
}

__global__ void hist_kernel(const int* __restrict__ dst, int* __restrict__ cnt, int E) {
    int gid = blockIdx.x * 256 + threadIdx.x;
    if (gid < E) atomicAdd(&cnt[dst[gid]], 1);
}

// ---------- 3-phase parallel exclusive scan over cnt[0..NN) ----------

__global__ __launch_bounds__(256) void blocksum_kernel(const int* __restrict__ cnt,
                                                       int* __restrict__ bsum, int n) {
    __shared__ int sm[256];
    int t = threadIdx.x;
    int idx = blockIdx.x * 256 + t;
    sm[t] = (idx < n) ? cnt[idx] : 0;
    __syncthreads();
    for (int off = 128; off > 0; off >>= 1) {
        if (t < off) sm[t] += sm[t + off];
        __syncthreads();
    }
    if (t == 0) bsum[blockIdx.x] = sm[0];
}

__global__ __launch_bounds__(256) void scanb_kernel(const int* __restrict__ bsum,
                                                    int* __restrict__ bpre, int nb) {
    __shared__ int sm[256];
    int t = threadIdx.x;
    sm[t] = (t < nb) ? bsum[t] : 0;
    __syncthreads();
    for (int off = 1; off < 256; off <<= 1) {
        int v = sm[t];
        int add = (t >= off) ? sm[t - off] : 0;
        __syncthreads();
        sm[t] = v + add;
        __syncthreads();
    }
    if (t < nb) bpre[t] = (t == 0) ? 0 : sm[t - 1];
}

__global__ __launch_bounds__(256) void scatter_scan_kernel(const int* __restrict__ cnt,
                                                           const int* __restrict__ bpre,
                                                           int* __restrict__ row_start,
                                                           int* __restrict__ cursor, int n) {
    __shared__ int sm[256];
    int t = threadIdx.x;
    int idx = blockIdx.x * 256 + t;
    int val = (idx < n) ? cnt[idx] : 0;
    sm[t] = val;
    __syncthreads();
    for (int off = 1; off < 256; off <<= 1) {
        int v = sm[t];
        int add = (t >= off) ? sm[t - off] : 0;
        __syncthreads();
        sm[t] = v + add;
        __syncthreads();
    }
    int base = bpre[blockIdx.x] + sm[t] - val;   // exclusive prefix
    if (idx < n) { row_start[idx] = base; cursor[idx] = base; }
}

__global__ void build_kernel(const int* __restrict__ src, const int* __restrict__ dst,
                             int* __restrict__ cursor, int* __restrict__ srcs, int E) {
    int gid = blockIdx.x * 256 + threadIdx.x;
    if (gid >= E) return;
    int slot = atomicAdd(&cursor[dst[gid]], 1);
    srcs[slot] = src[gid];
}

// ---------- gather-mean: one wave per node, lane owns DV=D/64 columns ----------

template<int DV>
__global__ __launch_bounds__(256) void gather_mean_kernel(
    const short* __restrict__ h, const int* __restrict__ srcs,
    const int* __restrict__ row_start, const int* __restrict__ cnt,
    short* __restrict__ nb)
{
    typedef __attribute__((ext_vector_type(DV))) short svec;
    const int wave = threadIdx.x >> 6;
    const int lane = threadIdx.x & 63;
    const int v = blockIdx.x * 4 + wave;
    if (v >= NN) return;
    const int c  = cnt[v];
    const int rs = row_start[v];
    float acc[DV];
    #pragma unroll
    for (int j = 0; j < DV; ++j) acc[j] = 0.f;
    const svec* hp = (const svec*)h;   // row = 64 svecs
    int i = 0;
    for (; i + 4 <= c; i += 4) {
        int s0 = srcs[rs + i + 0];
        int s1 = srcs[rs + i + 1];
        int s2 = srcs[rs + i + 2];
        int s3 = srcs[rs + i + 3];
        svec v0 = hp[(long)s0 * 64 + lane];
        svec v1 = hp[(long)s1 * 64 + lane];
        svec v2 = hp[(long)s2 * 64 + lane];
        svec v3 = hp[(long)s3 * 64 + lane];
        #pragma unroll
        for (int j = 0; j < DV; ++j)
            acc[j] += (bf2f(v0[j]) + bf2f(v1[j])) + (bf2f(v2[j]) + bf2f(v3[j]));
    }
    for (; i < c; ++i) {
        svec vv = hp[(long)srcs[rs + i] * 64 + lane];
        #pragma unroll
        for (int j = 0; j < DV; ++j) acc[j] += bf2f(vv[j]);
    }
    float inv = (c > 0) ? (1.0f / (float)c) : 0.0f;
    svec outv;
    #pragma unroll
    for (int j = 0; j < DV; ++j) outv[j] = f2bf(acc[j] * inv);
    ((svec*)nb)[(long)v * 64 + lane] = outv;
}

// ---------- fused SAGE layer GEMM, LDS-staged ----------
// out = act(Aself@Bself^T + Aneigh@Bneigh^T + bias)
// A*: [M][KK] bf16 row-major (read ONCE, staged in LDS double-buffer w/ XOR swizzle)
// B*: [NOUT][KK] bf16 (weights, L2-resident, register-loaded)
// BM=64, BK=64, 512 threads = 8 waves. NOUT=256: waves 2x4; NOUT=128: waves 4x2.
template<int NOUT, int KK, bool RELU, bool OUT_F32>
__global__ __launch_bounds__(512, 4) void gemm_sage2_kernel(
    const short* __restrict__ Aself, const short* __restrict__ Aneigh,
    const short* __restrict__ Bself, const short* __restrict__ Bneigh,
    const float* __restrict__ bias, void* __restrict__ outp, int M)
{
    constexpr int WN = NOUT / 64;          // waves along N (4 or 2)
    constexpr int WM = 8 / WN;             // waves along M (2 or 4)
    constexpr int MR = 64 / (WM * 16);     // 16-row frags per wave (2 or 1)
    constexpr int NR = 4;                  // 16-col frags per wave (64 cols)
    constexpr int KT = KK / 64;            // k-tiles per phase
    constexpr int NT = 2 * KT;             // total tiles (self + neigh)

    __shared__ short lds[2][4096];         // 2 x [64 rows][64 k] bf16, 16 KB

    const int tid  = threadIdx.x;
    const int wave = tid >> 6;
    const int lane = tid & 63;
    const int wm = wave / WN;
    const int wn = wave % WN;
    const int l15 = lane & 15;
    const int kg  = lane >> 4;
    const int bm  = blockIdx.x * 64;

    // staging coords: linear LDS dest byte = tid*16; pre-swizzled global source
    const int srow = tid >> 3;                                  // 0..63
    const int scol = (((tid & 7) << 4) ^ ((srow & 7) << 4));    // byte in 128B row

    f32x4 acc[MR][NR];
    #pragma unroll
    for (int a = 0; a < MR; ++a)
        #pragma unroll
        for (int b = 0; b < NR; ++b)
            acc[a][b] = (f32x4){0.f, 0.f, 0.f, 0.f};

    auto stage = [&](int buf, int t) {
        int ph = t / KT, kt = t - ph * KT;
        const short* A = ph ? Aneigh : Aself;
        const short* gp = A + (size_t)(bm + srow) * KK + kt * 64 + (scol >> 1);
        __builtin_amdgcn_global_load_lds(
            (const __attribute__((address_space(1))) u32*)gp,
            (__attribute__((address_space(3))) u32*)(&lds[buf][wave << 9]),
            16, 0, 0);
    };

    stage(0, 0);
    __syncthreads();

    for (int t = 0; t < NT; ++t) {
        const int cur = t & 1;
        if (t + 1 < NT) stage(cur ^ 1, t + 1);

        // weight fragments for this tile (global, L2-hot)
        const int ph = t / KT, kt = t - ph * KT;
        const short* __restrict__ B = ph ? Bneigh : Bself;
        short8 breg[NR][2];
        #pragma unroll
        for (int nr = 0; nr < NR; ++nr) {
            const short* bp = B + (size_t)(wn * 64 + nr * 16 + l15) * KK + kt * 64 + kg * 8;
            breg[nr][0] = *(const short8*)bp;
            breg[nr][1] = *(const short8*)(bp + 32);
        }

        #pragma unroll
        for (int ks = 0; ks < 2; ++ks) {
            short8 areg[MR];
            #pragma unroll
            for (int mr = 0; mr < MR; ++mr) {
                int r = wm * (MR * 16) + mr * 16 + l15;
                int boff = r * 128 + ((ks * 64 + kg * 16) ^ ((r & 7) << 4));
                areg[mr] = *(const short8*)((const char*)lds[cur] + boff);
            }
            #pragma unroll
            for (int mr = 0; mr < MR; ++mr)
                #pragma unroll
                for (int nr = 0; nr < NR; ++nr)
                    acc[mr][nr] = __builtin_amdgcn_mfma_f32_16x16x32_bf16(
                        areg[mr], breg[nr][ks], acc[mr][nr], 0, 0, 0);
        }
        __syncthreads();
    }

    // epilogue
    #pragma unroll
    for (int mr = 0; mr < MR; ++mr) {
        int rowb = bm + wm * (MR * 16) + mr * 16 + kg * 4;
        #pragma unroll
        for (int nr = 0; nr < NR; ++nr) {
            int col = wn * 64 + nr * 16 + l15;
            float bv = bias[col];
            #pragma unroll
            for (int r = 0; r < 4; ++r) {
                int row = rowb + r;
                if (row < M) {
                    float vv = acc[mr][nr][r] + bv;
                    if (RELU) vv = fmaxf(vv, 0.f);
                    if (OUT_F32) ((float*)outp)[(size_t)row * NOUT + col] = vv;
                    else         ((short*)outp)[(size_t)row * NOUT + col] = f2bf(vv);
                }
            }
        }
    }
}

// ---------- launch ----------

extern "C" void kernel_launch(void* const* d_in, const int* in_sizes, int n_in,
                              void* d_out, int out_size, void* d_ws, size_t ws_size,
                              hipStream_t stream) {
    const float* x    = (const float*)d_in[0];
    const int*   srcp = (const int*)d_in[1];
    const int*   dstp = (const int*)d_in[2];
    const float* Ws0  = (const float*)d_in[3];
    const float* Wn0  = (const float*)d_in[4];
    const float* b0   = (const float*)d_in[5];
    const float* Ws1  = (const float*)d_in[6];
    const float* Wn1  = (const float*)d_in[7];
    const float* b1   = (const float*)d_in[8];
    const float* Ws2  = (const float*)d_in[9];
    const float* Wn2  = (const float*)d_in[10];
    const float* b2   = (const float*)d_in[11];

    char* base = (char*)d_ws;
    size_t off = 0;
    auto alloc = [&](size_t bytes) -> void* {
        void* p = base + off;
        off += (bytes + 255) & ~(size_t)255;
        return p;
    };

    int*   cnt       = (int*)alloc((size_t)NN * 4);
    int*   row_start = (int*)alloc((size_t)NN * 4);
    int*   cursor    = (int*)alloc((size_t)NN * 4);
    int*   bsum      = (int*)alloc((size_t)NB1 * 4);
    int*   bpre      = (int*)alloc((size_t)NB1 * 4);
    int*   srcs      = (int*)alloc((size_t)NE * 4);
    short* hA        = (short*)alloc((size_t)NN * 256 * 2);
    short* hB        = (short*)alloc((size_t)NN * 256 * 2);
    short* nb        = (short*)alloc((size_t)NN * 256 * 2);
    short* wts       = (short*)alloc((size_t)262144 * 2);
    short* Wt0s = wts;            // [256][128]
    short* Wt0n = Wt0s + 32768;   // [256][128]
    short* Wt1s = Wt0n + 32768;   // [256][256]
    short* Wt1n = Wt1s + 65536;   // [256][256]
    short* Wt2s = Wt1n + 65536;   // [128][256]
    short* Wt2n = Wt2s + 32768;   // [128][256]

    // CSR build (dst-sorted src list)
    hipMemsetAsync(cnt, 0, (size_t)NN * 4, stream);
    hist_kernel<<<(NE + 255) / 256, 256, 0, stream>>>(dstp, cnt, NE);
    blocksum_kernel<<<NB1, 256, 0, stream>>>(cnt, bsum, NN);
    scanb_kernel<<<1, 256, 0, stream>>>(bsum, bpre, NB1);
    scatter_scan_kernel<<<NB1, 256, 0, stream>>>(cnt, bpre, row_start, cursor, NN);
    build_kernel<<<(NE + 255) / 256, 256, 0, stream>>>(srcp, dstp, cursor, srcs, NE);

    // weight conversion/transpose to bf16 [Dout][K], single launch
    wcvt_all_kernel<<<1024, 256, 0, stream>>>(Ws0, Wn0, Ws1, Wn1, Ws2, Wn2, wts);

    // x -> bf16
    cvt_f32_bf16_kernel<<<(NN * 128 + 255) / 256, 256, 0, stream>>>(x, hA, NN * 128);

    const int mblocks = (NN + 63) / 64;   // 782
    const int gblocks = (NN + 3) / 4;     // 12500

    // layer 0: h0 [N,128] -> h1 [N,256] (relu)
    gather_mean_kernel<2><<<gblocks, 256, 0, stream>>>(hA, srcs, row_start, cnt, nb);
    gemm_sage2_kernel<256, 128, true, false><<<mblocks, 512, 0, stream>>>(
        hA, nb, Wt0s, Wt0n, b0, hB, NN);

    // layer 1: h1 [N,256] -> h2 [N,256] (relu)
    gather_mean_kernel<4><<<gblocks, 256, 0, stream>>>(hB, srcs, row_start, cnt, nb);
    gemm_sage2_kernel<256, 256, true, false><<<mblocks, 512, 0, stream>>>(
        hB, nb, Wt1s, Wt1n, b1, hA, NN);

    // layer 2: h2 [N,256] -> out [N,128] f32 (no relu)
    gather_mean_kernel<4><<<gblocks, 256, 0, stream>>>(hA, srcs, row_start, cnt, nb);
    gemm_sage2_kernel<128, 256, false, true><<<mblocks, 512, 0, stream>>>(
        hA, nb, Wt2s, Wt2n, b2, d_out, NN);
}

// Round 4
// 328.760 us; speedup vs baseline: 1.9931x; 1.3296x over previous
//
#include <hip/hip_runtime.h>

#define NN 50000
#define NE 800000
#define NB1 196   // ceil(NN/256)

typedef __attribute__((ext_vector_type(8))) short short8;
typedef __attribute__((ext_vector_type(4))) float f32x4;
typedef unsigned int u32;

__device__ __forceinline__ float bf2f(short u) {
    union { unsigned int i; float f; } c;
    c.i = ((unsigned int)(unsigned short)u) << 16;
    return c.f;
}
__device__ __forceinline__ short f2bf(float f) {
    union { float f; unsigned int i; } c; c.f = f;
    unsigned int u = c.i;
    unsigned int r = (u + 0x7FFFu + ((u >> 16) & 1u)) >> 16;
    return (short)r;
}

// ---------- small utility kernels ----------

__global__ void cvt_f32_bf16_kernel(const float* __restrict__ in, short* __restrict__ out, int n) {
    int gid = blockIdx.x * 256 + threadIdx.x;
    if (gid < n) out[gid] = f2bf(in[gid]);
}

// Weights -> bf16 swizzled tile blobs: per matrix layout [kt][d][64] shorts,
// element (k,d) stored at  kt*Dout*64 + d*64 + (kl ^ ((d&7)<<3)),  kt=k>>6, kl=k&63.
// A linear copy of one kt-blob into LDS gives rows of 128B whose byte b holds
// source k-byte (b ^ ((d&7)<<4)) — matching the ds_read swizzle in the GEMM.
__global__ void wcvt_all_kernel(const float* __restrict__ Ws0, const float* __restrict__ Wn0,
                                const float* __restrict__ Ws1, const float* __restrict__ Wn1,
                                const float* __restrict__ Ws2, const float* __restrict__ Wn2,
                                short* __restrict__ wts) {
    int gid = blockIdx.x * 256 + threadIdx.x;   // 0..262143
    const float* W; int K, Dout, base, loc;
    if (gid < 65536)       { K = 128; Dout = 256; base = (gid < 32768)  ? 0 : 32768;
                             W = (gid < 32768)  ? Ws0 : Wn0; loc = gid & 32767; }
    else if (gid < 196608) { K = 256; Dout = 256; base = (gid < 131072) ? 65536 : 131072;
                             W = (gid < 131072) ? Ws1 : Wn1; loc = (gid - 65536) & 65535; }
    else                   { K = 256; Dout = 128; base = (gid < 229376) ? 196608 : 229376;
                             W = (gid < 229376) ? Ws2 : Wn2; loc = (gid - 196608) & 32767; }
    int k = loc / Dout, d = loc - k * Dout;
    int kt = k >> 6, kl = k & 63;
    wts[base + kt * Dout * 64 + d * 64 + (kl ^ ((d & 7) << 3))] = f2bf(W[(long)k * Dout + d]);
}

__global__ void hist_kernel(const int* __restrict__ dst, int* __restrict__ cnt, int E) {
    int gid = blockIdx.x * 256 + threadIdx.x;
    if (gid < E) atomicAdd(&cnt[dst[gid]], 1);
}

// ---------- 3-phase parallel exclusive scan over cnt[0..NN) ----------

__global__ __launch_bounds__(256) void blocksum_kernel(const int* __restrict__ cnt,
                                                       int* __restrict__ bsum, int n) {
    __shared__ int sm[256];
    int t = threadIdx.x;
    int idx = blockIdx.x * 256 + t;
    sm[t] = (idx < n) ? cnt[idx] : 0;
    __syncthreads();
    for (int off = 128; off > 0; off >>= 1) {
        if (t < off) sm[t] += sm[t + off];
        __syncthreads();
    }
    if (t == 0) bsum[blockIdx.x] = sm[0];
}

__global__ __launch_bounds__(256) void scanb_kernel(const int* __restrict__ bsum,
                                                    int* __restrict__ bpre, int nb) {
    __shared__ int sm[256];
    int t = threadIdx.x;
    sm[t] = (t < nb) ? bsum[t] : 0;
    __syncthreads();
    for (int off = 1; off < 256; off <<= 1) {
        int v = sm[t];
        int add = (t >= off) ? sm[t - off] : 0;
        __syncthreads();
        sm[t] = v + add;
        __syncthreads();
    }
    if (t < nb) bpre[t] = (t == 0) ? 0 : sm[t - 1];
}

__global__ __launch_bounds__(256) void scatter_scan_kernel(const int* __restrict__ cnt,
                                                           const int* __restrict__ bpre,
                                                           int* __restrict__ row_start,
                                                           int* __restrict__ cursor, int n) {
    __shared__ int sm[256];
    int t = threadIdx.x;
    int idx = blockIdx.x * 256 + t;
    int val = (idx < n) ? cnt[idx] : 0;
    sm[t] = val;
    __syncthreads();
    for (int off = 1; off < 256; off <<= 1) {
        int v = sm[t];
        int add = (t >= off) ? sm[t - off] : 0;
        __syncthreads();
        sm[t] = v + add;
        __syncthreads();
    }
    int base = bpre[blockIdx.x] + sm[t] - val;   // exclusive prefix
    if (idx < n) { row_start[idx] = base; cursor[idx] = base; }
}

__global__ void build_kernel(const int* __restrict__ src, const int* __restrict__ dst,
                             int* __restrict__ cursor, int* __restrict__ srcs, int E) {
    int gid = blockIdx.x * 256 + threadIdx.x;
    if (gid >= E) return;
    int slot = atomicAdd(&cursor[dst[gid]], 1);
    srcs[slot] = src[gid];
}

// ---------- gather-mean: one wave per node, lane owns DV=D/64 columns ----------

template<int DV>
__global__ __launch_bounds__(256) void gather_mean_kernel(
    const short* __restrict__ h, const int* __restrict__ srcs,
    const int* __restrict__ row_start, const int* __restrict__ cnt,
    short* __restrict__ nb)
{
    typedef __attribute__((ext_vector_type(DV))) short svec;
    const int wave = threadIdx.x >> 6;
    const int lane = threadIdx.x & 63;
    const int v = blockIdx.x * 4 + wave;
    if (v >= NN) return;
    const int c  = cnt[v];
    const int rs = row_start[v];
    float acc[DV];
    #pragma unroll
    for (int j = 0; j < DV; ++j) acc[j] = 0.f;
    const svec* hp = (const svec*)h;   // row = 64 svecs
    int i = 0;
    for (; i + 4 <= c; i += 4) {
        int s0 = srcs[rs + i + 0];
        int s1 = srcs[rs + i + 1];
        int s2 = srcs[rs + i + 2];
        int s3 = srcs[rs + i + 3];
        svec v0 = hp[(long)s0 * 64 + lane];
        svec v1 = hp[(long)s1 * 64 + lane];
        svec v2 = hp[(long)s2 * 64 + lane];
        svec v3 = hp[(long)s3 * 64 + lane];
        #pragma unroll
        for (int j = 0; j < DV; ++j)
            acc[j] += (bf2f(v0[j]) + bf2f(v1[j])) + (bf2f(v2[j]) + bf2f(v3[j]));
    }
    for (; i < c; ++i) {
        svec vv = hp[(long)srcs[rs + i] * 64 + lane];
        #pragma unroll
        for (int j = 0; j < DV; ++j) acc[j] += bf2f(vv[j]);
    }
    float inv = (c > 0) ? (1.0f / (float)c) : 0.0f;
    svec outv;
    #pragma unroll
    for (int j = 0; j < DV; ++j) outv[j] = f2bf(acc[j] * inv);
    ((svec*)nb)[(long)v * 64 + lane] = outv;
}

// ---------- fused SAGE layer GEMM, fully LDS-staged ----------
// out = act(Aself@Bself^T + Aneigh@Bneigh^T + bias)
// A*: [M][KK] bf16 row-major (read once, LDS dbuf, XOR swizzle via pre-swz source)
// B*: swizzled tile blobs [kt][NOUT][64] (see wcvt) -> linear-staged into LDS dbuf
// BM=128, BK=64, 512 threads = 8 waves (WM x WN), wave tile = (128/WM) x 64.
template<int NOUT, int KK, bool RELU, bool OUT_F32>
__global__ __launch_bounds__(512, 2) void gemm_sage3_kernel(
    const short* __restrict__ Aself, const short* __restrict__ Aneigh,
    const short* __restrict__ Bself, const short* __restrict__ Bneigh,
    const float* __restrict__ bias, void* __restrict__ outp, int M)
{
    constexpr int WN = NOUT / 64;          // col wave-groups (4 or 2)
    constexpr int WM = 8 / WN;             // row wave-groups (2 or 4)
    constexpr int MR = 128 / (WM * 16);    // 16-row frags per wave (4 or 2)
    constexpr int NR = 4;                  // 16-col frags per wave (64 cols)
    constexpr int KT = KK / 64;            // k-tiles per operand
    constexpr int NT = 2 * KT;             // total tiles (self + neigh)
    constexpr int WC = NOUT / 64;          // 8KB stage calls for W tile

    __shared__ short ldsA[2][128 * 64];    // 2 x 16 KB
    __shared__ short ldsW[2][NOUT * 64];   // 2 x (32 or 16) KB

    const int tid  = threadIdx.x;
    const int wave = tid >> 6;
    const int lane = tid & 63;
    const int wm = wave / WN;
    const int wn = wave % WN;
    const int l15 = lane & 15;
    const int kg  = lane >> 4;
    const int bm  = blockIdx.x * 128;

    f32x4 acc[MR][NR];
    #pragma unroll
    for (int a = 0; a < MR; ++a)
        #pragma unroll
        for (int b = 0; b < NR; ++b)
            acc[a][b] = (f32x4){0.f, 0.f, 0.f, 0.f};

    const int srow = tid >> 3;                                // 0..63
    const int scol = ((tid & 7) << 3) ^ ((srow & 7) << 3);    // shorts, pre-swizzled src

    auto stageA = [&](int buf, int t) {
        int ph = t / KT, kt = t - ph * KT;
        const short* A = ph ? Aneigh : Aself;
        #pragma unroll
        for (int c = 0; c < 2; ++c) {
            const short* gp = A + (size_t)(bm + c * 64 + srow) * KK + kt * 64 + scol;
            __builtin_amdgcn_global_load_lds(
                (const __attribute__((address_space(1))) u32*)gp,
                (__attribute__((address_space(3))) u32*)(&ldsA[buf][c * 4096 + (wave << 9)]),
                16, 0, 0);
        }
    };
    auto stageW = [&](int buf, int t) {
        int ph = t / KT, kt = t - ph * KT;
        const short* Wm = (ph ? Bneigh : Bself) + (size_t)kt * NOUT * 64 + tid * 8;
        #pragma unroll
        for (int c = 0; c < WC; ++c) {
            __builtin_amdgcn_global_load_lds(
                (const __attribute__((address_space(1))) u32*)(Wm + c * 4096),
                (__attribute__((address_space(3))) u32*)(&ldsW[buf][c * 4096 + (wave << 9)]),
                16, 0, 0);
        }
    };

    stageA(0, 0);
    stageW(0, 0);
    __syncthreads();

    for (int t = 0; t < NT; ++t) {
        const int cur = t & 1;
        if (t + 1 < NT) { stageA(cur ^ 1, t + 1); stageW(cur ^ 1, t + 1); }

        #pragma unroll
        for (int ks = 0; ks < 2; ++ks) {
            short8 areg[MR], wreg[NR];
            #pragma unroll
            for (int mr = 0; mr < MR; ++mr) {
                int r = wm * (MR * 16) + mr * 16 + l15;
                areg[mr] = *(const short8*)(&ldsA[cur][r * 64 + ((ks * 32 + kg * 8) ^ ((r & 7) << 3))]);
            }
            #pragma unroll
            for (int nr = 0; nr < NR; ++nr) {
                int cl = wn * 64 + nr * 16 + l15;
                wreg[nr] = *(const short8*)(&ldsW[cur][cl * 64 + ((ks * 32 + kg * 8) ^ ((cl & 7) << 3))]);
            }
            #pragma unroll
            for (int mr = 0; mr < MR; ++mr)
                #pragma unroll
                for (int nr = 0; nr < NR; ++nr)
                    acc[mr][nr] = __builtin_amdgcn_mfma_f32_16x16x32_bf16(
                        areg[mr], wreg[nr], acc[mr][nr], 0, 0, 0);
        }
        __syncthreads();
    }

    // epilogue
    #pragma unroll
    for (int mr = 0; mr < MR; ++mr) {
        int rowb = bm + wm * (MR * 16) + mr * 16 + kg * 4;
        #pragma unroll
        for (int nr = 0; nr < NR; ++nr) {
            int col = wn * 64 + nr * 16 + l15;
            float bv = bias[col];
            #pragma unroll
            for (int r = 0; r < 4; ++r) {
                int row = rowb + r;
                if (row < M) {
                    float vv = acc[mr][nr][r] + bv;
                    if (RELU) vv = fmaxf(vv, 0.f);
                    if (OUT_F32) ((float*)outp)[(size_t)row * NOUT + col] = vv;
                    else         ((short*)outp)[(size_t)row * NOUT + col] = f2bf(vv);
                }
            }
        }
    }
}

// ---------- launch ----------

extern "C" void kernel_launch(void* const* d_in, const int* in_sizes, int n_in,
                              void* d_out, int out_size, void* d_ws, size_t ws_size,
                              hipStream_t stream) {
    const float* x    = (const float*)d_in[0];
    const int*   srcp = (const int*)d_in[1];
    const int*   dstp = (const int*)d_in[2];
    const float* Ws0  = (const float*)d_in[3];
    const float* Wn0  = (const float*)d_in[4];
    const float* b0   = (const float*)d_in[5];
    const float* Ws1  = (const float*)d_in[6];
    const float* Wn1  = (const float*)d_in[7];
    const float* b1   = (const float*)d_in[8];
    const float* Ws2  = (const float*)d_in[9];
    const float* Wn2  = (const float*)d_in[10];
    const float* b2   = (const float*)d_in[11];

    char* base = (char*)d_ws;
    size_t off = 0;
    auto alloc = [&](size_t bytes) -> void* {
        void* p = base + off;
        off += (bytes + 255) & ~(size_t)255;
        return p;
    };

    int*   cnt       = (int*)alloc((size_t)NN * 4);
    int*   row_start = (int*)alloc((size_t)NN * 4);
    int*   cursor    = (int*)alloc((size_t)NN * 4);
    int*   bsum      = (int*)alloc((size_t)NB1 * 4);
    int*   bpre      = (int*)alloc((size_t)NB1 * 4);
    int*   srcs      = (int*)alloc((size_t)NE * 4);
    short* hA        = (short*)alloc((size_t)NN * 256 * 2);
    short* hB        = (short*)alloc((size_t)NN * 256 * 2);
    short* nb        = (short*)alloc((size_t)NN * 256 * 2);
    short* wts       = (short*)alloc((size_t)262144 * 2 + 65536);  // +slack for OOB row staging
    short* Wt0s = wts;            // blobs, see wcvt_all_kernel
    short* Wt0n = Wt0s + 32768;
    short* Wt1s = Wt0n + 32768;
    short* Wt1n = Wt1s + 65536;
    short* Wt2s = Wt1n + 65536;
    short* Wt2n = Wt2s + 32768;

    // CSR build (dst-sorted src list)
    hipMemsetAsync(cnt, 0, (size_t)NN * 4, stream);
    hist_kernel<<<(NE + 255) / 256, 256, 0, stream>>>(dstp, cnt, NE);
    blocksum_kernel<<<NB1, 256, 0, stream>>>(cnt, bsum, NN);
    scanb_kernel<<<1, 256, 0, stream>>>(bsum, bpre, NB1);
    scatter_scan_kernel<<<NB1, 256, 0, stream>>>(cnt, bpre, row_start, cursor, NN);
    build_kernel<<<(NE + 255) / 256, 256, 0, stream>>>(srcp, dstp, cursor, srcs, NE);

    // weight conversion -> swizzled bf16 blobs, single launch
    wcvt_all_kernel<<<1024, 256, 0, stream>>>(Ws0, Wn0, Ws1, Wn1, Ws2, Wn2, wts);

    // x -> bf16
    cvt_f32_bf16_kernel<<<(NN * 128 + 255) / 256, 256, 0, stream>>>(x, hA, NN * 128);

    const int mblocks = (NN + 127) / 128;   // 391
    const int gblocks = (NN + 3) / 4;       // 12500

    // layer 0: h0 [N,128] -> h1 [N,256] (relu)
    gather_mean_kernel<2><<<gblocks, 256, 0, stream>>>(hA, srcs, row_start, cnt, nb);
    gemm_sage3_kernel<256, 128, true, false><<<mblocks, 512, 0, stream>>>(
        hA, nb, Wt0s, Wt0n, b0, hB, NN);

    // layer 1: h1 [N,256] -> h2 [N,256] (relu)
    gather_mean_kernel<4><<<gblocks, 256, 0, stream>>>(hB, srcs, row_start, cnt, nb);
    gemm_sage3_kernel<256, 256, true, false><<<mblocks, 512, 0, stream>>>(
        hB, nb, Wt1s, Wt1n, b1, hA, NN);

    // layer 2: h2 [N,256] -> out [N,128] f32 (no relu)
    gather_mean_kernel<4><<<gblocks, 256, 0, stream>>>(hA, srcs, row_start, cnt, nb);
    gemm_sage3_kernel<128, 256, false, true><<<mblocks, 512, 0, stream>>>(
        hA, nb, Wt2s, Wt2n, b2, d_out, NN);
}

// Round 5
// 313.719 us; speedup vs baseline: 2.0887x; 1.0479x over previous
//
#include <hip/hip_runtime.h>

#define NN 50000
#define NE 800000
#define NB1 196   // ceil(NN/256)

typedef __attribute__((ext_vector_type(8))) short short8;
typedef __attribute__((ext_vector_type(4))) float f32x4;
typedef unsigned int u32;

__device__ __forceinline__ float bf2f(short u) {
    union { unsigned int i; float f; } c;
    c.i = ((unsigned int)(unsigned short)u) << 16;
    return c.f;
}
__device__ __forceinline__ short f2bf(float f) {
    union { float f; unsigned int i; } c; c.f = f;
    unsigned int u = c.i;
    unsigned int r = (u + 0x7FFFu + ((u >> 16) & 1u)) >> 16;
    return (short)r;
}

// ---------- small utility kernels ----------

__global__ void cvt_f32_bf16_kernel(const float* __restrict__ in, short* __restrict__ out, int n) {
    int gid = blockIdx.x * 256 + threadIdx.x;
    if (gid < n) out[gid] = f2bf(in[gid]);
}

// Weights -> bf16 swizzled tile blobs: per matrix layout [kt][d][64] shorts,
// element (k,d) stored at  kt*Dout*64 + d*64 + (kl ^ ((d&7)<<3)),  kt=k>>6, kl=k&63.
__global__ void wcvt_all_kernel(const float* __restrict__ Ws0, const float* __restrict__ Wn0,
                                const float* __restrict__ Ws1, const float* __restrict__ Wn1,
                                const float* __restrict__ Ws2, const float* __restrict__ Wn2,
                                short* __restrict__ wts) {
    int gid = blockIdx.x * 256 + threadIdx.x;   // 0..262143
    const float* W; int K, Dout, base, loc;
    if (gid < 65536)       { K = 128; Dout = 256; base = (gid < 32768)  ? 0 : 32768;
                             W = (gid < 32768)  ? Ws0 : Wn0; loc = gid & 32767; }
    else if (gid < 196608) { K = 256; Dout = 256; base = (gid < 131072) ? 65536 : 131072;
                             W = (gid < 131072) ? Ws1 : Wn1; loc = (gid - 65536) & 65535; }
    else                   { K = 256; Dout = 128; base = (gid < 229376) ? 196608 : 229376;
                             W = (gid < 229376) ? Ws2 : Wn2; loc = (gid - 196608) & 32767; }
    int k = loc / Dout, d = loc - k * Dout;
    int kt = k >> 6, kl = k & 63;
    wts[base + kt * Dout * 64 + d * 64 + (kl ^ ((d & 7) << 3))] = f2bf(W[(long)k * Dout + d]);
}

__global__ void hist_kernel(const int* __restrict__ dst, int* __restrict__ cnt, int E) {
    int gid = blockIdx.x * 256 + threadIdx.x;
    if (gid < E) atomicAdd(&cnt[dst[gid]], 1);
}

// ---------- 3-phase parallel exclusive scan over cnt[0..NN) ----------

__global__ __launch_bounds__(256) void blocksum_kernel(const int* __restrict__ cnt,
                                                       int* __restrict__ bsum, int n) {
    __shared__ int sm[256];
    int t = threadIdx.x;
    int idx = blockIdx.x * 256 + t;
    sm[t] = (idx < n) ? cnt[idx] : 0;
    __syncthreads();
    for (int off = 128; off > 0; off >>= 1) {
        if (t < off) sm[t] += sm[t + off];
        __syncthreads();
    }
    if (t == 0) bsum[blockIdx.x] = sm[0];
}

__global__ __launch_bounds__(256) void scanb_kernel(const int* __restrict__ bsum,
                                                    int* __restrict__ bpre, int nb) {
    __shared__ int sm[256];
    int t = threadIdx.x;
    sm[t] = (t < nb) ? bsum[t] : 0;
    __syncthreads();
    for (int off = 1; off < 256; off <<= 1) {
        int v = sm[t];
        int add = (t >= off) ? sm[t - off] : 0;
        __syncthreads();
        sm[t] = v + add;
        __syncthreads();
    }
    if (t < nb) bpre[t] = (t == 0) ? 0 : sm[t - 1];
}

__global__ __launch_bounds__(256) void scatter_scan_kernel(const int* __restrict__ cnt,
                                                           const int* __restrict__ bpre,
                                                           int* __restrict__ row_start,
                                                           int* __restrict__ cursor, int n) {
    __shared__ int sm[256];
    int t = threadIdx.x;
    int idx = blockIdx.x * 256 + t;
    int val = (idx < n) ? cnt[idx] : 0;
    sm[t] = val;
    __syncthreads();
    for (int off = 1; off < 256; off <<= 1) {
        int v = sm[t];
        int add = (t >= off) ? sm[t - off] : 0;
        __syncthreads();
        sm[t] = v + add;
        __syncthreads();
    }
    int base = bpre[blockIdx.x] + sm[t] - val;   // exclusive prefix
    if (idx < n) { row_start[idx] = base; cursor[idx] = base; }
}

__global__ void build_kernel(const int* __restrict__ src, const int* __restrict__ dst,
                             int* __restrict__ cursor, int* __restrict__ srcs, int E) {
    int gid = blockIdx.x * 256 + threadIdx.x;
    if (gid >= E) return;
    int slot = atomicAdd(&cursor[dst[gid]], 1);
    srcs[slot] = src[gid];
}

// ---------- gather-mean v2: wave per node, EPL edges per load, 16B/lane ----------
// lane = slot*CPR + cg; each load instr covers EPL edge-rows; slot streams are
// independent (more MLP); butterfly shfl_xor combines slots at the end.

template<int D>
__global__ __launch_bounds__(256) void gather_mean2_kernel(
    const short* __restrict__ h, const int* __restrict__ srcs,
    const int* __restrict__ row_start, const int* __restrict__ cnt,
    short* __restrict__ nb)
{
    constexpr int CPR = D / 8;        // short8 groups per row (16 or 32)
    constexpr int EPL = 64 / CPR;     // edges per wave-load (4 or 2)
    const int wave = threadIdx.x >> 6;
    const int lane = threadIdx.x & 63;
    const int v = blockIdx.x * 4 + wave;
    if (v >= NN) return;
    const int c  = cnt[v];
    const int rs = row_start[v];
    const int slot = lane / CPR;
    const int cg   = lane & (CPR - 1);
    float acc[8];
    #pragma unroll
    for (int j = 0; j < 8; ++j) acc[j] = 0.f;
    const short8* hp = (const short8*)h;
    int i = slot;
    // 4 loads in flight per lane
    for (; i + 3 * EPL < c; i += 4 * EPL) {
        int s0 = srcs[rs + i];
        int s1 = srcs[rs + i + EPL];
        int s2 = srcs[rs + i + 2 * EPL];
        int s3 = srcs[rs + i + 3 * EPL];
        short8 v0 = hp[(size_t)s0 * CPR + cg];
        short8 v1 = hp[(size_t)s1 * CPR + cg];
        short8 v2 = hp[(size_t)s2 * CPR + cg];
        short8 v3 = hp[(size_t)s3 * CPR + cg];
        #pragma unroll
        for (int j = 0; j < 8; ++j)
            acc[j] += (bf2f(v0[j]) + bf2f(v1[j])) + (bf2f(v2[j]) + bf2f(v3[j]));
    }
    for (; i < c; i += EPL) {
        int s0 = srcs[rs + i];
        short8 v0 = hp[(size_t)s0 * CPR + cg];
        #pragma unroll
        for (int j = 0; j < 8; ++j) acc[j] += bf2f(v0[j]);
    }
    // combine slot partial sums (lane bits above log2(CPR))
    #pragma unroll
    for (int j = 0; j < 8; ++j) {
        if (EPL == 4) acc[j] += __shfl_xor(acc[j], 16);
        acc[j] += __shfl_xor(acc[j], 32);
    }
    if (slot == 0) {
        float inv = (c > 0) ? (1.0f / (float)c) : 0.0f;
        short8 outv;
        #pragma unroll
        for (int j = 0; j < 8; ++j) outv[j] = f2bf(acc[j] * inv);
        ((short8*)nb)[(size_t)v * CPR + cg] = outv;
    }
}

// ---------- fused SAGE layer GEMM, fully LDS-staged ----------
// out = act(A@B0^T [+ Aneigh@B1^T] + bias [+ addin])
// A: [M][KK] bf16 (LDS dbuf, XOR swizzle); B*: swizzled blobs [kt][NOUT][64]
// BM=128, BK=64, 512 threads = 8 waves.
template<int NOUT, int KK, int PHASES, bool RELU, bool OUT_F32, bool ADDIN, bool BIAS>
__global__ __launch_bounds__(512, 2) void gemm_sage3_kernel(
    const short* __restrict__ Aself, const short* __restrict__ Aneigh,
    const short* __restrict__ Bself, const short* __restrict__ Bneigh,
    const float* __restrict__ bias, void* __restrict__ outp, int M,
    const short* __restrict__ addin)
{
    constexpr int WN = NOUT / 64;          // col wave-groups (4 or 2)
    constexpr int WM = 8 / WN;             // row wave-groups (2 or 4)
    constexpr int MR = 128 / (WM * 16);    // 16-row frags per wave (4 or 2)
    constexpr int NR = 4;                  // 16-col frags per wave (64 cols)
    constexpr int KT = KK / 64;            // k-tiles per operand
    constexpr int NT = PHASES * KT;        // total tiles
    constexpr int WC = NOUT / 64;          // 8KB stage calls for W tile

    __shared__ short ldsA[2][128 * 64];    // 2 x 16 KB
    __shared__ short ldsW[2][NOUT * 64];   // 2 x (32 or 16) KB

    const int tid  = threadIdx.x;
    const int wave = tid >> 6;
    const int lane = tid & 63;
    const int wm = wave / WN;
    const int wn = wave % WN;
    const int l15 = lane & 15;
    const int kg  = lane >> 4;
    const int bm  = blockIdx.x * 128;

    f32x4 acc[MR][NR];
    #pragma unroll
    for (int a = 0; a < MR; ++a)
        #pragma unroll
        for (int b = 0; b < NR; ++b)
            acc[a][b] = (f32x4){0.f, 0.f, 0.f, 0.f};

    const int srow = tid >> 3;                                // 0..63
    const int scol = ((tid & 7) << 3) ^ ((srow & 7) << 3);    // shorts, pre-swizzled src

    auto stageA = [&](int buf, int t) {
        int ph = t / KT, kt = t - ph * KT;
        const short* A = ph ? Aneigh : Aself;
        #pragma unroll
        for (int c = 0; c < 2; ++c) {
            const short* gp = A + (size_t)(bm + c * 64 + srow) * KK + kt * 64 + scol;
            __builtin_amdgcn_global_load_lds(
                (const __attribute__((address_space(1))) u32*)gp,
                (__attribute__((address_space(3))) u32*)(&ldsA[buf][c * 4096 + (wave << 9)]),
                16, 0, 0);
        }
    };
    auto stageW = [&](int buf, int t) {
        int ph = t / KT, kt = t - ph * KT;
        const short* Wm = (ph ? Bneigh : Bself) + (size_t)kt * NOUT * 64 + tid * 8;
        #pragma unroll
        for (int c = 0; c < WC; ++c) {
            __builtin_amdgcn_global_load_lds(
                (const __attribute__((address_space(1))) u32*)(Wm + c * 4096),
                (__attribute__((address_space(3))) u32*)(&ldsW[buf][c * 4096 + (wave << 9)]),
                16, 0, 0);
        }
    };

    stageA(0, 0);
    stageW(0, 0);
    __syncthreads();

    for (int t = 0; t < NT; ++t) {
        const int cur = t & 1;
        if (t + 1 < NT) { stageA(cur ^ 1, t + 1); stageW(cur ^ 1, t + 1); }

        #pragma unroll
        for (int ks = 0; ks < 2; ++ks) {
            short8 areg[MR], wreg[NR];
            #pragma unroll
            for (int mr = 0; mr < MR; ++mr) {
                int r = wm * (MR * 16) + mr * 16 + l15;
                areg[mr] = *(const short8*)(&ldsA[cur][r * 64 + ((ks * 32 + kg * 8) ^ ((r & 7) << 3))]);
            }
            #pragma unroll
            for (int nr = 0; nr < NR; ++nr) {
                int cl = wn * 64 + nr * 16 + l15;
                wreg[nr] = *(const short8*)(&ldsW[cur][cl * 64 + ((ks * 32 + kg * 8) ^ ((cl & 7) << 3))]);
            }
            #pragma unroll
            for (int mr = 0; mr < MR; ++mr)
                #pragma unroll
                for (int nr = 0; nr < NR; ++nr)
                    acc[mr][nr] = __builtin_amdgcn_mfma_f32_16x16x32_bf16(
                        areg[mr], wreg[nr], acc[mr][nr], 0, 0, 0);
        }
        __syncthreads();
    }

    // epilogue
    #pragma unroll
    for (int mr = 0; mr < MR; ++mr) {
        int rowb = bm + wm * (MR * 16) + mr * 16 + kg * 4;
        #pragma unroll
        for (int nr = 0; nr < NR; ++nr) {
            int col = wn * 64 + nr * 16 + l15;
            float bv = BIAS ? bias[col] : 0.f;
            #pragma unroll
            for (int r = 0; r < 4; ++r) {
                int row = rowb + r;
                if (row < M) {
                    float vv = acc[mr][nr][r] + bv;
                    if (ADDIN) vv += bf2f(addin[(size_t)row * NOUT + col]);
                    if (RELU) vv = fmaxf(vv, 0.f);
                    if (OUT_F32) ((float*)outp)[(size_t)row * NOUT + col] = vv;
                    else         ((short*)outp)[(size_t)row * NOUT + col] = f2bf(vv);
                }
            }
        }
    }
}

// ---------- launch ----------

extern "C" void kernel_launch(void* const* d_in, const int* in_sizes, int n_in,
                              void* d_out, int out_size, void* d_ws, size_t ws_size,
                              hipStream_t stream) {
    const float* x    = (const float*)d_in[0];
    const int*   srcp = (const int*)d_in[1];
    const int*   dstp = (const int*)d_in[2];
    const float* Ws0  = (const float*)d_in[3];
    const float* Wn0  = (const float*)d_in[4];
    const float* b0   = (const float*)d_in[5];
    const float* Ws1  = (const float*)d_in[6];
    const float* Wn1  = (const float*)d_in[7];
    const float* b1   = (const float*)d_in[8];
    const float* Ws2  = (const float*)d_in[9];
    const float* Wn2  = (const float*)d_in[10];
    const float* b2   = (const float*)d_in[11];

    char* base = (char*)d_ws;
    size_t off = 0;
    auto alloc = [&](size_t bytes) -> void* {
        void* p = base + off;
        off += (bytes + 255) & ~(size_t)255;
        return p;
    };

    int*   cnt       = (int*)alloc((size_t)NN * 4);
    int*   row_start = (int*)alloc((size_t)NN * 4);
    int*   cursor    = (int*)alloc((size_t)NN * 4);
    int*   bsum      = (int*)alloc((size_t)NB1 * 4);
    int*   bpre      = (int*)alloc((size_t)NB1 * 4);
    int*   srcs      = (int*)alloc((size_t)NE * 4);
    short* hA        = (short*)alloc((size_t)NN * 256 * 2);
    short* hB        = (short*)alloc((size_t)NN * 256 * 2);
    short* nb        = (short*)alloc((size_t)NN * 256 * 2);
    short* wts       = (short*)alloc((size_t)262144 * 2 + 65536);
    short* Wt0s = wts;            // blobs, see wcvt_all_kernel
    short* Wt0n = Wt0s + 32768;
    short* Wt1s = Wt0n + 32768;
    short* Wt1n = Wt1s + 65536;
    short* Wt2s = Wt1n + 65536;
    short* Wt2n = Wt2s + 32768;

    // CSR build (dst-sorted src list)
    hipMemsetAsync(cnt, 0, (size_t)NN * 4, stream);
    hist_kernel<<<(NE + 255) / 256, 256, 0, stream>>>(dstp, cnt, NE);
    blocksum_kernel<<<NB1, 256, 0, stream>>>(cnt, bsum, NN);
    scanb_kernel<<<1, 256, 0, stream>>>(bsum, bpre, NB1);
    scatter_scan_kernel<<<NB1, 256, 0, stream>>>(cnt, bpre, row_start, cursor, NN);
    build_kernel<<<(NE + 255) / 256, 256, 0, stream>>>(srcp, dstp, cursor, srcs, NE);

    // weight conversion -> swizzled bf16 blobs, single launch
    wcvt_all_kernel<<<1024, 256, 0, stream>>>(Ws0, Wn0, Ws1, Wn1, Ws2, Wn2, wts);

    // x -> bf16
    cvt_f32_bf16_kernel<<<(NN * 128 + 255) / 256, 256, 0, stream>>>(x, hA, NN * 128);

    const int mblocks = (NN + 127) / 128;   // 391
    const int gblocks = (NN + 3) / 4;       // 12500

    // layer 0: h0 [N,128] -> h1 [N,256] (relu)   hB = relu(hA@Ws0 + gather(hA)@Wn0 + b0)
    gather_mean2_kernel<128><<<gblocks, 256, 0, stream>>>(hA, srcs, row_start, cnt, nb);
    gemm_sage3_kernel<256, 128, 2, true, false, false, true><<<mblocks, 512, 0, stream>>>(
        hA, nb, Wt0s, Wt0n, b0, hB, NN, nullptr);

    // layer 1: h1 [N,256] -> h2 [N,256] (relu)   hA = relu(hB@Ws1 + gather(hB)@Wn1 + b1)
    gather_mean2_kernel<256><<<gblocks, 256, 0, stream>>>(hB, srcs, row_start, cnt, nb);
    gemm_sage3_kernel<256, 256, 2, true, false, false, true><<<mblocks, 512, 0, stream>>>(
        hB, nb, Wt1s, Wt1n, b1, hA, NN, nullptr);

    // layer 2 (reordered): g = hA@Wn2 (bf16, D=128); nb = gather(g);
    //                      out = hA@Ws2 + b2 + nb   (f32)
    gemm_sage3_kernel<128, 256, 1, false, false, false, false><<<mblocks, 512, 0, stream>>>(
        hA, hA, Wt2n, Wt2n, nullptr, hB, NN, nullptr);
    gather_mean2_kernel<128><<<gblocks, 256, 0, stream>>>(hB, srcs, row_start, cnt, nb);
    gemm_sage3_kernel<128, 256, 1, false, true, true, true><<<mblocks, 512, 0, stream>>>(
        hA, hA, Wt2s, Wt2s, b2, d_out, NN, nb);
}

// Round 6
// 300.117 us; speedup vs baseline: 2.1833x; 1.0453x over previous
//
#include <hip/hip_runtime.h>

#define NN 50000
#define NE 800000
#define NCHK 200     // edge chunks (NCHK*CHKE == NE exactly)
#define CHKE 4000
#define NBUK 196     // dst>>8 buckets (50000/256 -> 196 covers 50176)
#define BCAP 5120    // per-bucket LDS capacity (mean 4082, sd 64 -> +16 sd)

typedef __attribute__((ext_vector_type(8))) short short8;
typedef __attribute__((ext_vector_type(4))) float f32x4;
typedef unsigned int u32;
typedef unsigned short u16;

__device__ __forceinline__ float bf2f(short u) {
    union { unsigned int i; float f; } c;
    c.i = ((unsigned int)(unsigned short)u) << 16;
    return c.f;
}
__device__ __forceinline__ short f2bf(float f) {
    union { float f; unsigned int i; } c; c.f = f;
    unsigned int u = c.i;
    unsigned int r = (u + 0x7FFFu + ((u >> 16) & 1u)) >> 16;
    return (short)r;
}

// ---------- small utility kernels ----------

__global__ void cvt_f32_bf16_kernel(const float* __restrict__ in, short* __restrict__ out, int n) {
    int gid = blockIdx.x * 256 + threadIdx.x;
    if (gid < n) out[gid] = f2bf(in[gid]);
}

// Weights -> bf16 swizzled tile blobs: per matrix layout [kt][d][64] shorts,
// element (k,d) stored at  kt*Dout*64 + d*64 + (kl ^ ((d&7)<<3)),  kt=k>>6, kl=k&63.
__global__ void wcvt_all_kernel(const float* __restrict__ Ws0, const float* __restrict__ Wn0,
                                const float* __restrict__ Ws1, const float* __restrict__ Wn1,
                                const float* __restrict__ Ws2, const float* __restrict__ Wn2,
                                short* __restrict__ wts) {
    int gid = blockIdx.x * 256 + threadIdx.x;   // 0..262143
    const float* W; int K, Dout, base, loc;
    if (gid < 65536)       { K = 128; Dout = 256; base = (gid < 32768)  ? 0 : 32768;
                             W = (gid < 32768)  ? Ws0 : Wn0; loc = gid & 32767; }
    else if (gid < 196608) { K = 256; Dout = 256; base = (gid < 131072) ? 65536 : 131072;
                             W = (gid < 131072) ? Ws1 : Wn1; loc = (gid - 65536) & 65535; }
    else                   { K = 256; Dout = 128; base = (gid < 229376) ? 196608 : 229376;
                             W = (gid < 229376) ? Ws2 : Wn2; loc = (gid - 196608) & 32767; }
    int k = loc / Dout, d = loc - k * Dout;
    int kt = k >> 6, kl = k & 63;
    wts[base + kt * Dout * 64 + d * 64 + (kl ^ ((d & 7) << 3))] = f2bf(W[(long)k * Dout + d]);
}

// ---------- bucketed CSR build ----------
// P1: per-chunk bucket histogram -> chist[k][b]
__global__ __launch_bounds__(256) void bucket_hist_kernel(const int* __restrict__ dst,
                                                          int* __restrict__ chist) {
    __shared__ int lh[NBUK];
    int b = blockIdx.x, t = threadIdx.x;
    for (int i = t; i < NBUK; i += 256) lh[i] = 0;
    __syncthreads();
    int base = b * CHKE;
    for (int i = t; i < CHKE; i += 256) atomicAdd(&lh[dst[base + i] >> 8], 1);
    __syncthreads();
    for (int i = t; i < NBUK; i += 256) chist[i * NCHK + b] = lh[i];
}

// P2: exclusive scan of chist (39200 entries, k-major) -> off
__global__ __launch_bounds__(256) void scan_off_kernel(const int* __restrict__ chist,
                                                       int* __restrict__ off) {
    __shared__ int part[256];
    const int n = NBUK * NCHK;
    int t = threadIdx.x;
    int per = (n + 255) / 256;
    int lo = t * per, hi = lo + per; if (hi > n) hi = n; if (lo > n) lo = n;
    int s = 0;
    for (int i = lo; i < hi; ++i) s += chist[i];
    part[t] = s;
    __syncthreads();
    for (int o = 1; o < 256; o <<= 1) {
        int v = part[t];
        int a = (t >= o) ? part[t - o] : 0;
        __syncthreads();
        part[t] = v + a;
        __syncthreads();
    }
    int run = (t == 0) ? 0 : part[t - 1];
    for (int i = lo; i < hi; ++i) { off[i] = run; run += chist[i]; }
}

// P3: scatter packed edges ((dst&255)<<16 | src) into bucketed runs
__global__ __launch_bounds__(256) void bucket_scatter_kernel(const int* __restrict__ src,
                                                             const int* __restrict__ dst,
                                                             const int* __restrict__ off,
                                                             u32* __restrict__ ebuf) {
    __shared__ int lcur[NBUK];
    int b = blockIdx.x, t = threadIdx.x;
    for (int i = t; i < NBUK; i += 256) lcur[i] = off[i * NCHK + b];
    __syncthreads();
    int base = b * CHKE;
    for (int i = t; i < CHKE; i += 256) {
        int d = dst[base + i], s = src[base + i];
        int slot = atomicAdd(&lcur[d >> 8], 1);
        ebuf[slot] = ((u32)(d & 255) << 16) | (u32)s;
    }
}

// P4: one block per bucket: LDS counting sort -> srcs16 (u16), row_start, cnt
__global__ __launch_bounds__(256) void bucket_sort_kernel(const u32* __restrict__ ebuf,
                                                          const int* __restrict__ off,
                                                          u16* __restrict__ srcs16,
                                                          int* __restrict__ row_start,
                                                          int* __restrict__ cnt) {
    __shared__ u32 earr[BCAP];
    __shared__ u16 s16[BCAP];
    __shared__ int lhist[256], lpre[256], lcur[256];
    int k = blockIdx.x, t = threadIdx.x;
    int base = off[k * NCHK];
    int end  = (k < NBUK - 1) ? off[(k + 1) * NCHK] : NE;
    int nE = end - base;
    lhist[t] = 0;
    __syncthreads();
    for (int i = t; i < nE; i += 256) {
        u32 e = ebuf[base + i];
        earr[i] = e;
        atomicAdd(&lhist[e >> 16], 1);
    }
    __syncthreads();
    int v = lhist[t];
    lpre[t] = v;
    __syncthreads();
    for (int o = 1; o < 256; o <<= 1) {
        int x = lpre[t];
        int a = (t >= o) ? lpre[t - o] : 0;
        __syncthreads();
        lpre[t] = x + a;
        __syncthreads();
    }
    int excl = lpre[t] - v;
    int node = k * 256 + t;
    if (node < NN) { row_start[node] = base + excl; cnt[node] = v; }
    lcur[t] = excl;
    __syncthreads();
    for (int i = t; i < nE; i += 256) {
        u32 e = earr[i];
        int pos = atomicAdd(&lcur[e >> 16], 1);
        s16[pos] = (u16)(e & 0xFFFFu);
    }
    __syncthreads();
    for (int i = t; i < nE; i += 256) srcs16[base + i] = s16[i];
}

// ---------- gather-mean: wave per node, EPL edges per load, 16B/lane ----------

template<int D>
__global__ __launch_bounds__(256) void gather_mean2_kernel(
    const short* __restrict__ h, const u16* __restrict__ srcs,
    const int* __restrict__ row_start, const int* __restrict__ cnt,
    short* __restrict__ nb)
{
    constexpr int CPR = D / 8;        // short8 groups per row (16 or 32)
    constexpr int EPL = 64 / CPR;     // edges per wave-load (4 or 2)
    const int wave = threadIdx.x >> 6;
    const int lane = threadIdx.x & 63;
    const int v = blockIdx.x * 4 + wave;
    if (v >= NN) return;
    const int c  = cnt[v];
    const int rs = row_start[v];
    const int slot = lane / CPR;
    const int cg   = lane & (CPR - 1);
    float acc[8];
    #pragma unroll
    for (int j = 0; j < 8; ++j) acc[j] = 0.f;
    const short8* hp = (const short8*)h;
    int i = slot;
    for (; i + 3 * EPL < c; i += 4 * EPL) {
        int s0 = srcs[rs + i];
        int s1 = srcs[rs + i + EPL];
        int s2 = srcs[rs + i + 2 * EPL];
        int s3 = srcs[rs + i + 3 * EPL];
        short8 v0 = hp[(size_t)s0 * CPR + cg];
        short8 v1 = hp[(size_t)s1 * CPR + cg];
        short8 v2 = hp[(size_t)s2 * CPR + cg];
        short8 v3 = hp[(size_t)s3 * CPR + cg];
        #pragma unroll
        for (int j = 0; j < 8; ++j)
            acc[j] += (bf2f(v0[j]) + bf2f(v1[j])) + (bf2f(v2[j]) + bf2f(v3[j]));
    }
    for (; i < c; i += EPL) {
        int s0 = srcs[rs + i];
        short8 v0 = hp[(size_t)s0 * CPR + cg];
        #pragma unroll
        for (int j = 0; j < 8; ++j) acc[j] += bf2f(v0[j]);
    }
    #pragma unroll
    for (int j = 0; j < 8; ++j) {
        if (EPL == 4) acc[j] += __shfl_xor(acc[j], 16);
        acc[j] += __shfl_xor(acc[j], 32);
    }
    if (slot == 0) {
        float inv = (c > 0) ? (1.0f / (float)c) : 0.0f;
        short8 outv;
        #pragma unroll
        for (int j = 0; j < 8; ++j) outv[j] = f2bf(acc[j] * inv);
        ((short8*)nb)[(size_t)v * CPR + cg] = outv;
    }
}

// ---------- fused SAGE layer GEMM, fully LDS-staged ----------
// out = act(A@B0^T [+ Aneigh@B1^T] + bias [+ addin])
// A: [M][KK] bf16 (LDS dbuf, XOR swizzle); B*: swizzled blobs [kt][NOUT][64]
// BM=128, BK=64, 512 threads = 8 waves.
template<int NOUT, int KK, int PHASES, bool RELU, bool OUT_F32, bool ADDIN, bool BIAS>
__global__ __launch_bounds__(512, 2) void gemm_sage3_kernel(
    const short* __restrict__ Aself, const short* __restrict__ Aneigh,
    const short* __restrict__ Bself, const short* __restrict__ Bneigh,
    const float* __restrict__ bias, void* __restrict__ outp, int M,
    const short* __restrict__ addin)
{
    constexpr int WN = NOUT / 64;          // col wave-groups (4 or 2)
    constexpr int WM = 8 / WN;             // row wave-groups (2 or 4)
    constexpr int MR = 128 / (WM * 16);    // 16-row frags per wave (4 or 2)
    constexpr int NR = 4;                  // 16-col frags per wave (64 cols)
    constexpr int KT = KK / 64;            // k-tiles per operand
    constexpr int NT = PHASES * KT;        // total tiles
    constexpr int WC = NOUT / 64;          // 8KB stage calls for W tile

    __shared__ short ldsA[2][128 * 64];    // 2 x 16 KB
    __shared__ short ldsW[2][NOUT * 64];   // 2 x (32 or 16) KB

    const int tid  = threadIdx.x;
    const int wave = tid >> 6;
    const int lane = tid & 63;
    const int wm = wave / WN;
    const int wn = wave % WN;
    const int l15 = lane & 15;
    const int kg  = lane >> 4;
    const int bm  = blockIdx.x * 128;

    f32x4 acc[MR][NR];
    #pragma unroll
    for (int a = 0; a < MR; ++a)
        #pragma unroll
        for (int b = 0; b < NR; ++b)
            acc[a][b] = (f32x4){0.f, 0.f, 0.f, 0.f};

    const int srow = tid >> 3;                                // 0..63
    const int scol = ((tid & 7) << 3) ^ ((srow & 7) << 3);    // shorts, pre-swizzled src

    auto stageA = [&](int buf, int t) {
        int ph = t / KT, kt = t - ph * KT;
        const short* A = ph ? Aneigh : Aself;
        #pragma unroll
        for (int c = 0; c < 2; ++c) {
            const short* gp = A + (size_t)(bm + c * 64 + srow) * KK + kt * 64 + scol;
            __builtin_amdgcn_global_load_lds(
                (const __attribute__((address_space(1))) u32*)gp,
                (__attribute__((address_space(3))) u32*)(&ldsA[buf][c * 4096 + (wave << 9)]),
                16, 0, 0);
        }
    };
    auto stageW = [&](int buf, int t) {
        int ph = t / KT, kt = t - ph * KT;
        const short* Wm = (ph ? Bneigh : Bself) + (size_t)kt * NOUT * 64 + tid * 8;
        #pragma unroll
        for (int c = 0; c < WC; ++c) {
            __builtin_amdgcn_global_load_lds(
                (const __attribute__((address_space(1))) u32*)(Wm + c * 4096),
                (__attribute__((address_space(3))) u32*)(&ldsW[buf][c * 4096 + (wave << 9)]),
                16, 0, 0);
        }
    };

    stageA(0, 0);
    stageW(0, 0);
    __syncthreads();

    for (int t = 0; t < NT; ++t) {
        const int cur = t & 1;
        if (t + 1 < NT) { stageA(cur ^ 1, t + 1); stageW(cur ^ 1, t + 1); }

        #pragma unroll
        for (int ks = 0; ks < 2; ++ks) {
            short8 areg[MR], wreg[NR];
            #pragma unroll
            for (int mr = 0; mr < MR; ++mr) {
                int r = wm * (MR * 16) + mr * 16 + l15;
                areg[mr] = *(const short8*)(&ldsA[cur][r * 64 + ((ks * 32 + kg * 8) ^ ((r & 7) << 3))]);
            }
            #pragma unroll
            for (int nr = 0; nr < NR; ++nr) {
                int cl = wn * 64 + nr * 16 + l15;
                wreg[nr] = *(const short8*)(&ldsW[cur][cl * 64 + ((ks * 32 + kg * 8) ^ ((cl & 7) << 3))]);
            }
            #pragma unroll
            for (int mr = 0; mr < MR; ++mr)
                #pragma unroll
                for (int nr = 0; nr < NR; ++nr)
                    acc[mr][nr] = __builtin_amdgcn_mfma_f32_16x16x32_bf16(
                        areg[mr], wreg[nr], acc[mr][nr], 0, 0, 0);
        }
        __syncthreads();
    }

    // epilogue
    #pragma unroll
    for (int mr = 0; mr < MR; ++mr) {
        int rowb = bm + wm * (MR * 16) + mr * 16 + kg * 4;
        #pragma unroll
        for (int nr = 0; nr < NR; ++nr) {
            int col = wn * 64 + nr * 16 + l15;
            float bv = BIAS ? bias[col] : 0.f;
            #pragma unroll
            for (int r = 0; r < 4; ++r) {
                int row = rowb + r;
                if (row < M) {
                    float vv = acc[mr][nr][r] + bv;
                    if (ADDIN) vv += bf2f(addin[(size_t)row * NOUT + col]);
                    if (RELU) vv = fmaxf(vv, 0.f);
                    if (OUT_F32) ((float*)outp)[(size_t)row * NOUT + col] = vv;
                    else         ((short*)outp)[(size_t)row * NOUT + col] = f2bf(vv);
                }
            }
        }
    }
}

// ---------- launch ----------

extern "C" void kernel_launch(void* const* d_in, const int* in_sizes, int n_in,
                              void* d_out, int out_size, void* d_ws, size_t ws_size,
                              hipStream_t stream) {
    const float* x    = (const float*)d_in[0];
    const int*   srcp = (const int*)d_in[1];
    const int*   dstp = (const int*)d_in[2];
    const float* Ws0  = (const float*)d_in[3];
    const float* Wn0  = (const float*)d_in[4];
    const float* b0   = (const float*)d_in[5];
    const float* Ws1  = (const float*)d_in[6];
    const float* Wn1  = (const float*)d_in[7];
    const float* b1   = (const float*)d_in[8];
    const float* Ws2  = (const float*)d_in[9];
    const float* Wn2  = (const float*)d_in[10];
    const float* b2   = (const float*)d_in[11];

    char* base = (char*)d_ws;
    size_t off_b = 0;
    auto alloc = [&](size_t bytes) -> void* {
        void* p = base + off_b;
        off_b += (bytes + 255) & ~(size_t)255;
        return p;
    };

    int*   cnt       = (int*)alloc((size_t)NN * 4);
    int*   row_start = (int*)alloc((size_t)NN * 4);
    int*   chist     = (int*)alloc((size_t)NBUK * NCHK * 4);
    int*   offb      = (int*)alloc((size_t)NBUK * NCHK * 4);
    u32*   ebuf      = (u32*)alloc((size_t)NE * 4);
    u16*   srcs16    = (u16*)alloc((size_t)NE * 2);
    short* hA        = (short*)alloc((size_t)NN * 256 * 2);
    short* hB        = (short*)alloc((size_t)NN * 256 * 2);
    short* nb        = (short*)alloc((size_t)NN * 256 * 2);
    short* wts       = (short*)alloc((size_t)262144 * 2 + 65536);
    short* Wt0s = wts;            // blobs, see wcvt_all_kernel
    short* Wt0n = Wt0s + 32768;
    short* Wt1s = Wt0n + 32768;
    short* Wt1n = Wt1s + 65536;
    short* Wt2s = Wt1n + 65536;
    short* Wt2n = Wt2s + 32768;

    // CSR build: bucketed counting sort (XCD-local final scatter)
    bucket_hist_kernel<<<NCHK, 256, 0, stream>>>(dstp, chist);
    scan_off_kernel<<<1, 256, 0, stream>>>(chist, offb);
    bucket_scatter_kernel<<<NCHK, 256, 0, stream>>>(srcp, dstp, offb, ebuf);
    bucket_sort_kernel<<<NBUK, 256, 0, stream>>>(ebuf, offb, srcs16, row_start, cnt);

    // weight conversion -> swizzled bf16 blobs, single launch
    wcvt_all_kernel<<<1024, 256, 0, stream>>>(Ws0, Wn0, Ws1, Wn1, Ws2, Wn2, wts);

    // x -> bf16
    cvt_f32_bf16_kernel<<<(NN * 128 + 255) / 256, 256, 0, stream>>>(x, hA, NN * 128);

    const int mblocks = (NN + 127) / 128;   // 391
    const int gblocks = (NN + 3) / 4;       // 12500

    // layer 0: h0 [N,128] -> h1 [N,256] (relu)   hB = relu(hA@Ws0 + gather(hA)@Wn0 + b0)
    gather_mean2_kernel<128><<<gblocks, 256, 0, stream>>>(hA, srcs16, row_start, cnt, nb);
    gemm_sage3_kernel<256, 128, 2, true, false, false, true><<<mblocks, 512, 0, stream>>>(
        hA, nb, Wt0s, Wt0n, b0, hB, NN, nullptr);

    // layer 1: h1 [N,256] -> h2 [N,256] (relu)   hA = relu(hB@Ws1 + gather(hB)@Wn1 + b1)
    gather_mean2_kernel<256><<<gblocks, 256, 0, stream>>>(hB, srcs16, row_start, cnt, nb);
    gemm_sage3_kernel<256, 256, 2, true, false, false, true><<<mblocks, 512, 0, stream>>>(
        hB, nb, Wt1s, Wt1n, b1, hA, NN, nullptr);

    // layer 2 (reordered): g = hA@Wn2 (bf16, D=128); nb = gather(g);
    //                      out = hA@Ws2 + b2 + nb   (f32)
    gemm_sage3_kernel<128, 256, 1, false, false, false, false><<<mblocks, 512, 0, stream>>>(
        hA, hA, Wt2n, Wt2n, nullptr, hB, NN, nullptr);
    gather_mean2_kernel<128><<<gblocks, 256, 0, stream>>>(hB, srcs16, row_start, cnt, nb);
    gemm_sage3_kernel<128, 256, 1, false, true, true, true><<<mblocks, 512, 0, stream>>>(
        hA, hA, Wt2s, Wt2s, b2, d_out, NN, nb);
}

// Round 7
// 243.161 us; speedup vs baseline: 2.6947x; 1.2342x over previous
//
#include <hip/hip_runtime.h>

#define NN 50000
#define NE 800000
#define NCHK 200     // edge chunks (NCHK*CHKE == NE exactly)
#define CHKE 4000
#define NBUK 196     // dst>>8 buckets (50000/256 -> 196 covers 50176)
#define BCAP 5120    // per-bucket LDS capacity (mean 4082, sd 64 -> +16 sd)
#define NOFF (NBUK * NCHK)          // 39200
#define NSB  ((NOFF + 255) / 256)   // 154 scan blocks

typedef __attribute__((ext_vector_type(8))) short short8;
typedef __attribute__((ext_vector_type(4))) float f32x4;
typedef unsigned int u32;
typedef unsigned short u16;

__device__ __forceinline__ float bf2f(short u) {
    union { unsigned int i; float f; } c;
    c.i = ((unsigned int)(unsigned short)u) << 16;
    return c.f;
}
__device__ __forceinline__ short f2bf(float f) {
    union { float f; unsigned int i; } c; c.f = f;
    unsigned int u = c.i;
    unsigned int r = (u + 0x7FFFu + ((u >> 16) & 1u)) >> 16;
    return (short)r;
}

// ---------- small utility kernels ----------

__global__ void cvt_f32_bf16_kernel(const float* __restrict__ in, short* __restrict__ out, int n) {
    int gid = blockIdx.x * 256 + threadIdx.x;
    if (gid < n) out[gid] = f2bf(in[gid]);
}

// Weights -> bf16 swizzled tile blobs: per matrix layout [kt][d][64] shorts,
// element (k,d) stored at  kt*Dout*64 + d*64 + (kl ^ ((d&7)<<3)),  kt=k>>6, kl=k&63.
__global__ void wcvt_all_kernel(const float* __restrict__ Ws0, const float* __restrict__ Wn0,
                                const float* __restrict__ Ws1, const float* __restrict__ Wn1,
                                const float* __restrict__ Ws2, const float* __restrict__ Wn2,
                                short* __restrict__ wts) {
    int gid = blockIdx.x * 256 + threadIdx.x;   // 0..262143
    const float* W; int K, Dout, base, loc;
    if (gid < 65536)       { K = 128; Dout = 256; base = (gid < 32768)  ? 0 : 32768;
                             W = (gid < 32768)  ? Ws0 : Wn0; loc = gid & 32767; }
    else if (gid < 196608) { K = 256; Dout = 256; base = (gid < 131072) ? 65536 : 131072;
                             W = (gid < 131072) ? Ws1 : Wn1; loc = (gid - 65536) & 65535; }
    else                   { K = 256; Dout = 128; base = (gid < 229376) ? 196608 : 229376;
                             W = (gid < 229376) ? Ws2 : Wn2; loc = (gid - 196608) & 32767; }
    int k = loc / Dout, d = loc - k * Dout;
    int kt = k >> 6, kl = k & 63;
    wts[base + kt * Dout * 64 + d * 64 + (kl ^ ((d & 7) << 3))] = f2bf(W[(long)k * Dout + d]);
}

// ---------- bucketed CSR build ----------
// P1: per-chunk bucket histogram -> chist[bucket][chunk]
__global__ __launch_bounds__(256) void bucket_hist_kernel(const int* __restrict__ dst,
                                                          int* __restrict__ chist) {
    __shared__ int lh[NBUK];
    int b = blockIdx.x, t = threadIdx.x;
    for (int i = t; i < NBUK; i += 256) lh[i] = 0;
    __syncthreads();
    int base = b * CHKE;
    for (int i = t; i < CHKE; i += 256) atomicAdd(&lh[dst[base + i] >> 8], 1);
    __syncthreads();
    for (int i = t; i < NBUK; i += 256) chist[i * NCHK + b] = lh[i];
}

// P2: 3-phase parallel exclusive scan of chist[0..NOFF) -> off
__global__ __launch_bounds__(256) void off_blocksum_kernel(const int* __restrict__ in,
                                                           int* __restrict__ bsum) {
    __shared__ int sm[256];
    int t = threadIdx.x;
    int idx = blockIdx.x * 256 + t;
    sm[t] = (idx < NOFF) ? in[idx] : 0;
    __syncthreads();
    for (int off = 128; off > 0; off >>= 1) {
        if (t < off) sm[t] += sm[t + off];
        __syncthreads();
    }
    if (t == 0) bsum[blockIdx.x] = sm[0];
}

__global__ __launch_bounds__(256) void off_scanb_kernel(const int* __restrict__ bsum,
                                                        int* __restrict__ bpre) {
    __shared__ int sm[256];
    int t = threadIdx.x;
    sm[t] = (t < NSB) ? bsum[t] : 0;
    __syncthreads();
    for (int o = 1; o < 256; o <<= 1) {
        int v = sm[t];
        int a = (t >= o) ? sm[t - o] : 0;
        __syncthreads();
        sm[t] = v + a;
        __syncthreads();
    }
    if (t < NSB) bpre[t] = (t == 0) ? 0 : sm[t - 1];
}

__global__ __launch_bounds__(256) void off_scatter_kernel(const int* __restrict__ in,
                                                          const int* __restrict__ bpre,
                                                          int* __restrict__ off) {
    __shared__ int sm[256];
    int t = threadIdx.x;
    int idx = blockIdx.x * 256 + t;
    int val = (idx < NOFF) ? in[idx] : 0;
    sm[t] = val;
    __syncthreads();
    for (int o = 1; o < 256; o <<= 1) {
        int v = sm[t];
        int a = (t >= o) ? sm[t - o] : 0;
        __syncthreads();
        sm[t] = v + a;
        __syncthreads();
    }
    if (idx < NOFF) off[idx] = bpre[blockIdx.x] + sm[t] - val;   // exclusive
}

// P3: scatter packed edges ((dst&255)<<16 | src) into bucketed runs
__global__ __launch_bounds__(256) void bucket_scatter_kernel(const int* __restrict__ src,
                                                             const int* __restrict__ dst,
                                                             const int* __restrict__ off,
                                                             u32* __restrict__ ebuf) {
    __shared__ int lcur[NBUK];
    int b = blockIdx.x, t = threadIdx.x;
    for (int i = t; i < NBUK; i += 256) lcur[i] = off[i * NCHK + b];
    __syncthreads();
    int base = b * CHKE;
    for (int i = t; i < CHKE; i += 256) {
        int d = dst[base + i], s = src[base + i];
        int slot = atomicAdd(&lcur[d >> 8], 1);
        ebuf[slot] = ((u32)(d & 255) << 16) | (u32)s;
    }
}

// P4: one block per bucket: LDS counting sort -> srcs16 (u16), row_start, cnt
__global__ __launch_bounds__(256) void bucket_sort_kernel(const u32* __restrict__ ebuf,
                                                          const int* __restrict__ off,
                                                          u16* __restrict__ srcs16,
                                                          int* __restrict__ row_start,
                                                          int* __restrict__ cnt) {
    __shared__ u32 earr[BCAP];
    __shared__ u16 s16[BCAP];
    __shared__ int lhist[256], lpre[256], lcur[256];
    int k = blockIdx.x, t = threadIdx.x;
    int base = off[k * NCHK];
    int end  = (k < NBUK - 1) ? off[(k + 1) * NCHK] : NE;
    int nE = end - base;
    lhist[t] = 0;
    __syncthreads();
    for (int i = t; i < nE; i += 256) {
        u32 e = ebuf[base + i];
        earr[i] = e;
        atomicAdd(&lhist[e >> 16], 1);
    }
    __syncthreads();
    int v = lhist[t];
    lpre[t] = v;
    __syncthreads();
    for (int o = 1; o < 256; o <<= 1) {
        int x = lpre[t];
        int a = (t >= o) ? lpre[t - o] : 0;
        __syncthreads();
        lpre[t] = x + a;
        __syncthreads();
    }
    int excl = lpre[t] - v;
    int node = k * 256 + t;
    if (node < NN) { row_start[node] = base + excl; cnt[node] = v; }
    lcur[t] = excl;
    __syncthreads();
    for (int i = t; i < nE; i += 256) {
        u32 e = earr[i];
        int pos = atomicAdd(&lcur[e >> 16], 1);
        s16[pos] = (u16)(e & 0xFFFFu);
    }
    __syncthreads();
    for (int i = t; i < nE; i += 256) srcs16[base + i] = s16[i];
}

// ---------- gather-mean: wave per node, EPL edges per load, 16B/lane ----------

template<int D>
__global__ __launch_bounds__(256) void gather_mean2_kernel(
    const short* __restrict__ h, const u16* __restrict__ srcs,
    const int* __restrict__ row_start, const int* __restrict__ cnt,
    short* __restrict__ nb)
{
    constexpr int CPR = D / 8;        // short8 groups per row (16 or 32)
    constexpr int EPL = 64 / CPR;     // edges per wave-load (4 or 2)
    const int wave = threadIdx.x >> 6;
    const int lane = threadIdx.x & 63;
    const int v = blockIdx.x * 4 + wave;
    if (v >= NN) return;
    const int c  = cnt[v];
    const int rs = row_start[v];
    const int slot = lane / CPR;
    const int cg   = lane & (CPR - 1);
    float acc[8];
    #pragma unroll
    for (int j = 0; j < 8; ++j) acc[j] = 0.f;
    const short8* hp = (const short8*)h;
    int i = slot;
    for (; i + 3 * EPL < c; i += 4 * EPL) {
        int s0 = srcs[rs + i];
        int s1 = srcs[rs + i + EPL];
        int s2 = srcs[rs + i + 2 * EPL];
        int s3 = srcs[rs + i + 3 * EPL];
        short8 v0 = hp[(size_t)s0 * CPR + cg];
        short8 v1 = hp[(size_t)s1 * CPR + cg];
        short8 v2 = hp[(size_t)s2 * CPR + cg];
        short8 v3 = hp[(size_t)s3 * CPR + cg];
        #pragma unroll
        for (int j = 0; j < 8; ++j)
            acc[j] += (bf2f(v0[j]) + bf2f(v1[j])) + (bf2f(v2[j]) + bf2f(v3[j]));
    }
    for (; i < c; i += EPL) {
        int s0 = srcs[rs + i];
        short8 v0 = hp[(size_t)s0 * CPR + cg];
        #pragma unroll
        for (int j = 0; j < 8; ++j) acc[j] += bf2f(v0[j]);
    }
    #pragma unroll
    for (int j = 0; j < 8; ++j) {
        if (EPL == 4) acc[j] += __shfl_xor(acc[j], 16);
        acc[j] += __shfl_xor(acc[j], 32);
    }
    if (slot == 0) {
        float inv = (c > 0) ? (1.0f / (float)c) : 0.0f;
        short8 outv;
        #pragma unroll
        for (int j = 0; j < 8; ++j) outv[j] = f2bf(acc[j] * inv);
        ((short8*)nb)[(size_t)v * CPR + cg] = outv;
    }
}

// ---------- fused SAGE layer GEMM, fully LDS-staged ----------
// out = act(A@B0^T [+ Aneigh@B1^T] + bias [+ addin])
// A: [M][KK] bf16 (LDS dbuf, XOR swizzle); B*: swizzled blobs [kt][NOUT][64]
// BM=128, BK=64, 512 threads = 8 waves.
template<int NOUT, int KK, int PHASES, bool RELU, bool OUT_F32, bool ADDIN, bool BIAS>
__global__ __launch_bounds__(512, 2) void gemm_sage3_kernel(
    const short* __restrict__ Aself, const short* __restrict__ Aneigh,
    const short* __restrict__ Bself, const short* __restrict__ Bneigh,
    const float* __restrict__ bias, void* __restrict__ outp, int M,
    const short* __restrict__ addin)
{
    constexpr int WN = NOUT / 64;          // col wave-groups (4 or 2)
    constexpr int WM = 8 / WN;             // row wave-groups (2 or 4)
    constexpr int MR = 128 / (WM * 16);    // 16-row frags per wave (4 or 2)
    constexpr int NR = 4;                  // 16-col frags per wave (64 cols)
    constexpr int KT = KK / 64;            // k-tiles per operand
    constexpr int NT = PHASES * KT;        // total tiles
    constexpr int WC = NOUT / 64;          // 8KB stage calls for W tile

    __shared__ short ldsA[2][128 * 64];    // 2 x 16 KB
    __shared__ short ldsW[2][NOUT * 64];   // 2 x (32 or 16) KB

    const int tid  = threadIdx.x;
    const int wave = tid >> 6;
    const int lane = tid & 63;
    const int wm = wave / WN;
    const int wn = wave % WN;
    const int l15 = lane & 15;
    const int kg  = lane >> 4;
    const int bm  = blockIdx.x * 128;

    f32x4 acc[MR][NR];
    #pragma unroll
    for (int a = 0; a < MR; ++a)
        #pragma unroll
        for (int b = 0; b < NR; ++b)
            acc[a][b] = (f32x4){0.f, 0.f, 0.f, 0.f};

    const int srow = tid >> 3;                                // 0..63
    const int scol = ((tid & 7) << 3) ^ ((srow & 7) << 3);    // shorts, pre-swizzled src

    auto stageA = [&](int buf, int t) {
        int ph = t / KT, kt = t - ph * KT;
        const short* A = ph ? Aneigh : Aself;
        #pragma unroll
        for (int c = 0; c < 2; ++c) {
            const short* gp = A + (size_t)(bm + c * 64 + srow) * KK + kt * 64 + scol;
            __builtin_amdgcn_global_load_lds(
                (const __attribute__((address_space(1))) u32*)gp,
                (__attribute__((address_space(3))) u32*)(&ldsA[buf][c * 4096 + (wave << 9)]),
                16, 0, 0);
        }
    };
    auto stageW = [&](int buf, int t) {
        int ph = t / KT, kt = t - ph * KT;
        const short* Wm = (ph ? Bneigh : Bself) + (size_t)kt * NOUT * 64 + tid * 8;
        #pragma unroll
        for (int c = 0; c < WC; ++c) {
            __builtin_amdgcn_global_load_lds(
                (const __attribute__((address_space(1))) u32*)(Wm + c * 4096),
                (__attribute__((address_space(3))) u32*)(&ldsW[buf][c * 4096 + (wave << 9)]),
                16, 0, 0);
        }
    };

    stageA(0, 0);
    stageW(0, 0);
    __syncthreads();

    for (int t = 0; t < NT; ++t) {
        const int cur = t & 1;
        if (t + 1 < NT) { stageA(cur ^ 1, t + 1); stageW(cur ^ 1, t + 1); }

        #pragma unroll
        for (int ks = 0; ks < 2; ++ks) {
            short8 areg[MR], wreg[NR];
            #pragma unroll
            for (int mr = 0; mr < MR; ++mr) {
                int r = wm * (MR * 16) + mr * 16 + l15;
                areg[mr] = *(const short8*)(&ldsA[cur][r * 64 + ((ks * 32 + kg * 8) ^ ((r & 7) << 3))]);
            }
            #pragma unroll
            for (int nr = 0; nr < NR; ++nr) {
                int cl = wn * 64 + nr * 16 + l15;
                wreg[nr] = *(const short8*)(&ldsW[cur][cl * 64 + ((ks * 32 + kg * 8) ^ ((cl & 7) << 3))]);
            }
            #pragma unroll
            for (int mr = 0; mr < MR; ++mr)
                #pragma unroll
                for (int nr = 0; nr < NR; ++nr)
                    acc[mr][nr] = __builtin_amdgcn_mfma_f32_16x16x32_bf16(
                        areg[mr], wreg[nr], acc[mr][nr], 0, 0, 0);
        }
        __syncthreads();
    }

    // epilogue
    #pragma unroll
    for (int mr = 0; mr < MR; ++mr) {
        int rowb = bm + wm * (MR * 16) + mr * 16 + kg * 4;
        #pragma unroll
        for (int nr = 0; nr < NR; ++nr) {
            int col = wn * 64 + nr * 16 + l15;
            float bv = BIAS ? bias[col] : 0.f;
            #pragma unroll
            for (int r = 0; r < 4; ++r) {
                int row = rowb + r;
                if (row < M) {
                    float vv = acc[mr][nr][r] + bv;
                    if (ADDIN) vv += bf2f(addin[(size_t)row * NOUT + col]);
                    if (RELU) vv = fmaxf(vv, 0.f);
                    if (OUT_F32) ((float*)outp)[(size_t)row * NOUT + col] = vv;
                    else         ((short*)outp)[(size_t)row * NOUT + col] = f2bf(vv);
                }
            }
        }
    }
}

// ---------- launch ----------

extern "C" void kernel_launch(void* const* d_in, const int* in_sizes, int n_in,
                              void* d_out, int out_size, void* d_ws, size_t ws_size,
                              hipStream_t stream) {
    const float* x    = (const float*)d_in[0];
    const int*   srcp = (const int*)d_in[1];
    const int*   dstp = (const int*)d_in[2];
    const float* Ws0  = (const float*)d_in[3];
    const float* Wn0  = (const float*)d_in[4];
    const float* b0   = (const float*)d_in[5];
    const float* Ws1  = (const float*)d_in[6];
    const float* Wn1  = (const float*)d_in[7];
    const float* b1   = (const float*)d_in[8];
    const float* Ws2  = (const float*)d_in[9];
    const float* Wn2  = (const float*)d_in[10];
    const float* b2   = (const float*)d_in[11];

    char* base = (char*)d_ws;
    size_t off_b = 0;
    auto alloc = [&](size_t bytes) -> void* {
        void* p = base + off_b;
        off_b += (bytes + 255) & ~(size_t)255;
        return p;
    };

    int*   cnt       = (int*)alloc((size_t)NN * 4);
    int*   row_start = (int*)alloc((size_t)NN * 4);
    int*   chist     = (int*)alloc((size_t)NOFF * 4);
    int*   offb      = (int*)alloc((size_t)NOFF * 4);
    int*   bsum      = (int*)alloc((size_t)NSB * 4);
    int*   bpre      = (int*)alloc((size_t)NSB * 4);
    u32*   ebuf      = (u32*)alloc((size_t)NE * 4);
    u16*   srcs16    = (u16*)alloc((size_t)NE * 2);
    short* hA        = (short*)alloc((size_t)NN * 256 * 2);
    short* hB        = (short*)alloc((size_t)NN * 256 * 2);
    short* nb        = (short*)alloc((size_t)NN * 256 * 2);
    short* wts       = (short*)alloc((size_t)262144 * 2 + 65536);
    short* Wt0s = wts;            // blobs, see wcvt_all_kernel
    short* Wt0n = Wt0s + 32768;
    short* Wt1s = Wt0n + 32768;
    short* Wt1n = Wt1s + 65536;
    short* Wt2s = Wt1n + 65536;
    short* Wt2n = Wt2s + 32768;

    // CSR build: bucketed counting sort (XCD-local final scatter)
    bucket_hist_kernel<<<NCHK, 256, 0, stream>>>(dstp, chist);
    off_blocksum_kernel<<<NSB, 256, 0, stream>>>(chist, bsum);
    off_scanb_kernel<<<1, 256, 0, stream>>>(bsum, bpre);
    off_scatter_kernel<<<NSB, 256, 0, stream>>>(chist, bpre, offb);
    bucket_scatter_kernel<<<NCHK, 256, 0, stream>>>(srcp, dstp, offb, ebuf);
    bucket_sort_kernel<<<NBUK, 256, 0, stream>>>(ebuf, offb, srcs16, row_start, cnt);

    // weight conversion -> swizzled bf16 blobs, single launch
    wcvt_all_kernel<<<1024, 256, 0, stream>>>(Ws0, Wn0, Ws1, Wn1, Ws2, Wn2, wts);

    // x -> bf16
    cvt_f32_bf16_kernel<<<(NN * 128 + 255) / 256, 256, 0, stream>>>(x, hA, NN * 128);

    const int mblocks = (NN + 127) / 128;   // 391
    const int gblocks = (NN + 3) / 4;       // 12500

    // layer 0: h0 [N,128] -> h1 [N,256] (relu)   hB = relu(hA@Ws0 + gather(hA)@Wn0 + b0)
    gather_mean2_kernel<128><<<gblocks, 256, 0, stream>>>(hA, srcs16, row_start, cnt, nb);
    gemm_sage3_kernel<256, 128, 2, true, false, false, true><<<mblocks, 512, 0, stream>>>(
        hA, nb, Wt0s, Wt0n, b0, hB, NN, nullptr);

    // layer 1: h1 [N,256] -> h2 [N,256] (relu)   hA = relu(hB@Ws1 + gather(hB)@Wn1 + b1)
    gather_mean2_kernel<256><<<gblocks, 256, 0, stream>>>(hB, srcs16, row_start, cnt, nb);
    gemm_sage3_kernel<256, 256, 2, true, false, false, true><<<mblocks, 512, 0, stream>>>(
        hB, nb, Wt1s, Wt1n, b1, hA, NN, nullptr);

    // layer 2 (reordered): g = hA@Wn2 (bf16, D=128); nb = gather(g);
    //                      out = hA@Ws2 + b2 + nb   (f32)
    gemm_sage3_kernel<128, 256, 1, false, false, false, false><<<mblocks, 512, 0, stream>>>(
        hA, hA, Wt2n, Wt2n, nullptr, hB, NN, nullptr);
    gather_mean2_kernel<128><<<gblocks, 256, 0, stream>>>(hB, srcs16, row_start, cnt, nb);
    gemm_sage3_kernel<128, 256, 1, false, true, true, true><<<mblocks, 512, 0, stream>>>(
        hA, hA, Wt2s, Wt2s, b2, d_out, NN, nb);
}